// Round 17
// baseline (418.012 us; speedup 1.0000x reference)
//
#include <hip/hip_runtime.h>

typedef unsigned short u16;
typedef unsigned int u32;
typedef __bf16 bf16x8 __attribute__((ext_vector_type(8)));
typedef float f32x4 __attribute__((ext_vector_type(4)));
typedef u16 u16x8 __attribute__((ext_vector_type(8)));

#define S_    896
#define TR_   1643
#define NTOK_ 3286
#define MP_   3328   // 26*128 padded token rows (per-expert row capacity)

// ---------- helpers ----------
__device__ __forceinline__ u16 f2bf(float f) {
  u32 u = __builtin_bit_cast(u32, f);
  u = (u + 0x7FFFu + ((u >> 16) & 1u)) >> 16;   // RNE
  return (u16)u;
}

__device__ __forceinline__ void gload16(const void* g, void* l) {
  __builtin_amdgcn_global_load_lds(
      (const __attribute__((address_space(1))) u32*)g,
      (__attribute__((address_space(3))) u32*)l, 16, 0, 0);
}

// ---------- init: inverse permutation only ----------
__global__ void k_init(const int* __restrict__ index, int* __restrict__ inv) {
  int i = blockIdx.x * 256 + threadIdx.x;
  if (i < TR_) inv[index[i]] = i;
}

// ---------- xmean: single-pass column sum (round-16: no init, no atomics) ----------
__global__ __launch_bounds__(256)
void k_reduce_x(const float* __restrict__ x, float* __restrict__ xmean) {
  int i = blockIdx.x * 256 + threadIdx.x;   // 0..6143
  int b = i / 3072, d = i % 3072;
  const float* p = x + (size_t)b * S_ * 3072 + d;
  float s = 0.f;
  for (int t = 0; t < S_; ++t) s += p[(size_t)t * 3072];
  xmean[i] = s * (1.f / (float)S_);
}

// ---------- small gating, stage 1: 24 parallel dots ----------
__global__ __launch_bounds__(256)
void k_small_dots(const float* __restrict__ xmean,
                  const float* __restrict__ Wsel, const float* __restrict__ bsel,
                  const float* __restrict__ emb,  const float* __restrict__ Wemb,
                  const float* __restrict__ bemb, float* __restrict__ glel) {
  __shared__ float red[256];
  int blk = blockIdx.x, tid = threadIdx.x;
  float s = 0.f;
  if (blk < 16) {
    int b = blk >> 3, g = blk & 7;
    for (int d = tid; d < 3072; d += 256) s += xmean[b * 3072 + d] * Wsel[d * 8 + g];
  } else {
    int g = blk - 16;
    for (int d = tid; d < 1536; d += 256) s += emb[d] * Wemb[d * 8 + g];
  }
  red[tid] = s; __syncthreads();
  for (int st = 128; st > 0; st >>= 1) { if (tid < st) red[tid] += red[tid + st]; __syncthreads(); }
  if (tid == 0) glel[blk] = red[0] + (blk < 16 ? bsel[blk & 7] : bemb[blk - 16]);
}

// ---------- small gating, stage 2: tiny tail ----------
__global__ void k_small_tail(const float* __restrict__ glel,
                             float* __restrict__ w2buf, float* __restrict__ zpart,
                             float* __restrict__ outw) {
  if (threadIdx.x != 0) return;
  const float* gl = glel;
  const float* el = glel + 16;
  float zp = 0.f;
  for (int i = 0; i < 4; ++i) {
    float e0 = el[2 * i], e1 = el[2 * i + 1];
    float m = fmaxf(e0, e1);
    float x0 = expf(e0 - m), x1 = expf(e1 - m);
    float den = x0 + x1;
    float se0 = x0 / den, se1 = x1 / den;
    zp += (e0 * e0 + e1 * e1) * 0.5f;
    float tsq = 0.f;
    for (int b = 0; b < 2; ++b) {
      float t0 = gl[b * 8 + 2 * i], t1 = gl[b * 8 + 2 * i + 1];
      tsq += t0 * t0 + t1 * t1;
      float mm = fmaxf(t0, t1);
      float y0 = expf(t0 - mm), y1 = expf(t1 - mm);
      float dd = y0 + y1;
      float w0 = (y0 / dd + se0) * 0.5f, w1 = (y1 / dd + se1) * 0.5f;
      w2buf[b * 8 + 2 * i] = w0; w2buf[b * 8 + 2 * i + 1] = w1;
      outw[b * 8 + 2 * i]  = w0; outw[b * 8 + 2 * i + 1]  = w1;
    }
    zp += tsq * 0.25f;
  }
  *zpart = zp;
}

// ---------- gather (LDS-tiled transpose; writes o32 f32 + obf bf16 dense) ----------
__global__ __launch_bounds__(256)
void k_gather(const float* __restrict__ out_in, const int* __restrict__ inv,
              float* __restrict__ o32, u16* __restrict__ obf) {
  __shared__ float tile[32][33];
  int b = blockIdx.z;
  int tr0 = blockIdx.x * 32, s0 = blockIdx.y * 32;
  int tx = threadIdx.x & 31, ty = threadIdx.x >> 5;
  int ntr = TR_ - tr0; if (ntr > 32) ntr = 32;
  for (int i = ty; i < 32; i += 8)
    tile[i][tx] = (tx < ntr) ? out_in[((size_t)b * S_ + s0 + i) * TR_ + tr0 + tx] : 0.f;
  __syncthreads();
  for (int r = ty; r < ntr; r += 8) {
    int t = inv[tr0 + r];
    size_t off = ((size_t)b * TR_ + t) * S_ + s0 + tx;
    float v = tile[tx][r];
    o32[off] = v;
    obf[off] = f2bf(v);
  }
}

// ---------- per-token gating (no atomics) ----------
__global__ __launch_bounds__(256)
void k_gates(const float* __restrict__ o32, const float* __restrict__ temb,
             const float* __restrict__ Wg, const float* __restrict__ bg,
             const float* __restrict__ w2buf, float* __restrict__ gf,
             float* __restrict__ zbuf) {
  int n = blockIdx.x;
  int b = n / TR_, t = n % TR_;
  int typ = (t < 228) ? 0 : (t < 519) ? 1 : (t < 1286) ? 2 : 3;
  int tid = threadIdx.x;
  const float* orow = o32 + (size_t)n * S_;
  const float* trow = temb + typ * S_;
  const float* W0 = Wg + (size_t)(2 * typ) * S_ * 8;

  float acc[16];
#pragma unroll
  for (int k = 0; k < 16; ++k) acc[k] = 0.f;
  for (int s = tid; s < S_; s += 256) {
    float ov = orow[s] + trow[s];
    const float4* wa = (const float4*)(W0 + s * 8);
    const float4* wb = (const float4*)(W0 + 7168 + s * 8);
    float4 a0 = wa[0], a1 = wa[1], b0 = wb[0], b1 = wb[1];
    acc[0]  += ov * a0.x; acc[1]  += ov * a0.y; acc[2]  += ov * a0.z; acc[3]  += ov * a0.w;
    acc[4]  += ov * a1.x; acc[5]  += ov * a1.y; acc[6]  += ov * a1.z; acc[7]  += ov * a1.w;
    acc[8]  += ov * b0.x; acc[9]  += ov * b0.y; acc[10] += ov * b0.z; acc[11] += ov * b0.w;
    acc[12] += ov * b1.x; acc[13] += ov * b1.y; acc[14] += ov * b1.z; acc[15] += ov * b1.w;
  }
#pragma unroll
  for (int k = 0; k < 16; ++k)
#pragma unroll
    for (int m = 1; m < 64; m <<= 1) acc[k] += __shfl_xor(acc[k], m, 64);

  __shared__ float wsum[4][16];
  __shared__ float lgsh[16];
  int w = tid >> 6, lane = tid & 63;
  if (lane == 0)
#pragma unroll
    for (int k = 0; k < 16; ++k) wsum[w][k] = acc[k];
  __syncthreads();
  if (tid < 16)
    lgsh[tid] = wsum[0][tid] + wsum[1][tid] + wsum[2][tid] + wsum[3][tid]
              + bg[(2 * typ + (tid >> 3)) * 8 + (tid & 7)];
  __syncthreads();

  if (tid == 0) {
    float g[8];
    for (int k = 0; k < 8; ++k) g[k] = 0.f;
    float zs[2];
    for (int j = 0; j < 2; ++j) {
      float l[8]; float ss = 0.f;
      for (int k = 0; k < 8; ++k) {
        float v = lgsh[j * 8 + k];
        v = v > 0.f ? v : 0.01f * v;
        l[k] = v; ss += v * v;
      }
      zs[j] = ss;
      int i0 = 0;
      for (int k = 1; k < 8; ++k) if (l[k] > l[i0]) i0 = k;
      int i1 = -1;
      for (int k = 0; k < 8; ++k) { if (k == i0) continue; if (i1 < 0 || l[k] > l[i1]) i1 = k; }
      int i2 = -1;
      for (int k = 0; k < 8; ++k) { if (k == i0 || k == i1) continue; if (i2 < 0 || l[k] > l[i2]) i2 = k; }
      float p1 = expf(l[i1] - l[i0]), p2 = expf(l[i2] - l[i0]);
      float den = 1.f + p1 + p2;
      float w2 = w2buf[b * 8 + 2 * typ + j];
      g[i0] += w2 / den; g[i1] += w2 * p1 / den; g[i2] += w2 * p2 / den;
    }
    float* gfp = gf + (size_t)n * 8;
    for (int k = 0; k < 8; ++k) gfp[k] = g[k];
    zbuf[n * 2 + 0] = zs[0];
    zbuf[n * 2 + 1] = zs[1];
  }
}

// ---------- segment reductions ----------
__global__ __launch_bounds__(256)
void k_reduce_gates(const float* __restrict__ gf, const float* __restrict__ zbuf,
                    float* __restrict__ allg, float* __restrict__ zsum) {
  __shared__ float red[256];
  const int s0a[4] = {0, 228, 519, 1286};
  const int cta[4] = {228, 291, 767, 357};
  int blk = blockIdx.x, tid = threadIdx.x;
  float s = 0.f;
  if (blk < 32) {
    int typ = blk >> 3, e = blk & 7;
    int s0 = s0a[typ], cnt = cta[typ];
    for (int i = tid; i < 2 * cnt; i += 256) {
      int bb = i / cnt, tt = s0 + i % cnt;
      s += gf[(size_t)(bb * TR_ + tt) * 8 + e];
    }
  } else {
    int idx = blk - 32, typ = idx >> 1, j = idx & 1;
    int s0 = s0a[typ], cnt = cta[typ];
    for (int i = tid; i < 2 * cnt; i += 256) {
      int bb = i / cnt, tt = s0 + i % cnt;
      s += zbuf[(size_t)(bb * TR_ + tt) * 2 + j];
    }
  }
  red[tid] = s; __syncthreads();
  for (int st = 128; st > 0; st >>= 1) { if (tid < st) red[tid] += red[tid + st]; __syncthreads(); }
  if (tid == 0) {
    if (blk < 32) allg[blk] = red[0];
    else          zsum[blk - 32] = red[0];
  }
}

// ---------- expert token-list build + tail fill (round-16: tails -> token 0, gain 0) ----------
__global__ __launch_bounds__(256)
void k_build_lists(const float* __restrict__ gf, int* __restrict__ listE,
                   float* __restrict__ gcomp, int* __restrict__ posT,
                   int* __restrict__ cntE) {
  __shared__ int wcnt[4];
  __shared__ int sbase;
  int e = blockIdx.x;
  int tid = threadIdx.x, lane = tid & 63, wv = tid >> 6;
  if (tid == 0) sbase = 0;
  __syncthreads();
  for (int c = 0; c < 13; ++c) {
    int n = c * 256 + tid;
    float gv = (n < NTOK_) ? gf[(size_t)n * 8 + e] : 0.f;
    bool flag = (n < NTOK_) && (gv != 0.f);
    unsigned long long m = __ballot(flag);
    if (lane == 0) wcnt[wv] = __popcll(m);
    __syncthreads();
    int prefix = 0;
    for (int w = 0; w < 4; ++w) if (w < wv) prefix += wcnt[w];
    int within = __popcll(m & ((1ull << lane) - 1ull));
    if (n < NTOK_) {
      if (flag) {
        int idx = sbase + prefix + within;
        listE[e * MP_ + idx] = n;
        gcomp[e * MP_ + idx] = gv;
        posT[(size_t)n * 8 + e] = idx;
      } else {
        posT[(size_t)n * 8 + e] = -1;
      }
    }
    __syncthreads();
    if (tid == 0) sbase += wcnt[0] + wcnt[1] + wcnt[2] + wcnt[3];
    __syncthreads();
  }
  // tail fill: active-block tail rows must read valid memory and produce H=0
  for (int idx = sbase + tid; idx < MP_; idx += 256) {
    listE[e * MP_ + idx] = 0;
    gcomp[e * MP_ + idx] = 0.f;
  }
  if (tid == 0) cntE[e] = sbase;
}

// ---------- tiled transpose f32 -> bf16 with output-row padding ----------
__global__ __launch_bounds__(256)
void k_transpose(const float* __restrict__ W, u16* __restrict__ Wt,
                 int R, int C, int ldo, size_t eo) {
  __shared__ float tile[32][33];
  int e = blockIdx.z;
  const float* Wp = W + (size_t)e * R * C;
  u16* Wtp = Wt + (size_t)e * eo;
  int c0 = blockIdx.x * 32, r0 = blockIdx.y * 32;
  int tx = threadIdx.x & 31, ty = threadIdx.x >> 5;
  for (int i = ty; i < 32; i += 8)
    tile[i][tx] = (c0 + tx < C) ? Wp[(size_t)(r0 + i) * C + c0 + tx] : 0.f;
  __syncthreads();
  for (int i = ty; i < 32; i += 8) Wtp[(size_t)(c0 + i) * ldo + r0 + tx] = f2bf(tile[tx][i]);
}

// ---------- SPARSE 256x256x64 8-wave GEMM (frozen round-9 schedule) ----------
// MODE 1: A rows gathered IN-STAGING via listE (per-lane global src of
//         global_load_lds); A = dense obf. H_e = gcomp .* relu(... + b1_e).
// MODE 2: A = compact HbE rows (direct). Ye_e = H_e @ w2tE_e^T (bf16 out).
// Blocks early-exit when by*256 >= cntE[e] (grid static for graph capture).
template <int MODE>
__global__ __launch_bounds__(512, 2)
void k_gemm8s(const u16* __restrict__ A, const u16* __restrict__ Bt,
              const int* __restrict__ listE, const int* __restrict__ cntE,
              const float* __restrict__ gcomp, const float* __restrict__ bias,
              u16* __restrict__ H, u16* __restrict__ Ye) {
  __shared__ __align__(16) u16 lds[2 * 32768];   // [buf][A:16384|B:16384] u16
  const int tid = threadIdx.x;
  const int lane = tid & 63;
  const int wid = tid >> 6;
  const int wr = wid >> 2, wc = wid & 3;

  const int K   = (MODE == 1) ? 896 : 1792;
  const int lda = K, ldb = K;
  const int nx  = (MODE == 1) ? 7 : 4;
  const int n8  = (MODE == 1) ? 91 : 52;        // blocks per expert (13 * nx)
  const size_t bes = (MODE == 1) ? 1605632u : 1835008u;  // B expert stride (u16)

  int f0 = (blockIdx.z * 13 + blockIdx.y) * nx + blockIdx.x;
  int f = (f0 & 7) * n8 + (f0 >> 3);            // bijective XCD swizzle (8*n8 total)
  const int ez = f / n8;
  const int r8 = f % n8;
  const int by = r8 / nx, bx = r8 % nx;

  const int cnt = cntE[ez];
  if (by * 256 >= cnt) return;

  const int scol = ((lane & 7) ^ (lane >> 3)) << 3;   // inverse-swizzled col chunk
  const int rl   = wid * 8 + (lane >> 3);             // row_local base

  // per-thread A source base pointers for (g,q): row_local = q*128 + g*64 + rl
  const u16* aB00; const u16* aB01; const u16* aB10; const u16* aB11;
  if (MODE == 1) {
    const int* lE = listE + ez * MP_ + by * 256;
    aB00 = A + (size_t)lE[rl]       * 896 + scol;
    aB10 = A + (size_t)lE[64 + rl]  * 896 + scol;
    aB01 = A + (size_t)lE[128 + rl] * 896 + scol;
    aB11 = A + (size_t)lE[192 + rl] * 896 + scol;
  } else {
    const u16* Ag = A + ((size_t)ez * MP_ + (size_t)by * 256) * lda;
    aB00 = Ag + (size_t)rl * lda + scol;
    aB10 = Ag + (size_t)(64 + rl) * lda + scol;
    aB01 = Ag + (size_t)(128 + rl) * lda + scol;
    aB11 = Ag + (size_t)(192 + rl) * lda + scol;
  }
  const u16* Bg = Bt + (size_t)ez * bes + (size_t)(bx * 256) * ldb;
  const int NT = K >> 6;

#define SA(buf, g, k0)                                                          \
  {                                                                             \
    gload16((g ? aB10 : aB00) + (k0),                                           \
            lds + (buf) * 32768 + ((g) * 64 + wid * 8) * 64 + lane * 8);        \
    gload16((g ? aB11 : aB01) + (k0),                                           \
            lds + (buf) * 32768 + (128 + (g) * 64 + wid * 8) * 64 + lane * 8);  \
  }
#define SB(buf, g, k0)                                                          \
  { _Pragma("unroll")                                                           \
    for (int q = 0; q < 2; ++q) {                                               \
      const int sI = q * 8 + wid;                                               \
      const int br = (sI >> 2) * 64 + (g) * 32 + (sI & 3) * 8;                  \
      const int row = br + (lane >> 3);                                         \
      gload16(Bg + (size_t)row * ldb + scol + (k0),                             \
              lds + (buf) * 32768 + 16384 + br * 64 + lane * 8);                \
    } }
#define PSYNC(N)                                             \
  asm volatile("s_waitcnt vmcnt(" #N ")" ::: "memory");      \
  __builtin_amdgcn_s_barrier();                              \
  __builtin_amdgcn_sched_barrier(0);

  const int l15 = lane & 15, l16 = lane >> 4, l7 = lane & 7;
  const int swz0 = (l16 ^ l7) << 3;
  const int swz1 = ((4 + l16) ^ l7) << 3;
  const int rA = (wr * 128 + l15) * 64;
  const int rB = (wc * 64 + l15) * 64;

  f32x4 acc[8][4] = {};
  bf16x8 aF[4][2], b0F[2][2], b1F[2][2];

#define READ_A0  _Pragma("unroll") for (int i = 0; i < 4; ++i) {               \
    aF[i][0] = *(const bf16x8*)(lA + rA + i * 1024 + swz0);                    \
    aF[i][1] = *(const bf16x8*)(lA + rA + i * 1024 + swz1); }
#define READ_A1  _Pragma("unroll") for (int i = 0; i < 4; ++i) {               \
    aF[i][0] = *(const bf16x8*)(lA + rA + (i + 4) * 1024 + swz0);              \
    aF[i][1] = *(const bf16x8*)(lA + rA + (i + 4) * 1024 + swz1); }
#define READ_B0  _Pragma("unroll") for (int j = 0; j < 2; ++j) {               \
    b0F[j][0] = *(const bf16x8*)(lB + rB + j * 1024 + swz0);                   \
    b0F[j][1] = *(const bf16x8*)(lB + rB + j * 1024 + swz1); }
#define READ_B1  _Pragma("unroll") for (int j = 0; j < 2; ++j) {               \
    b1F[j][0] = *(const bf16x8*)(lB + rB + (j + 2) * 1024 + swz0);             \
    b1F[j][1] = *(const bf16x8*)(lB + rB + (j + 2) * 1024 + swz1); }
#define MFMA16(IB, JB, BF)                                                     \
  __builtin_amdgcn_s_setprio(1);                                               \
  _Pragma("unroll") for (int i = 0; i < 4; ++i)                                \
  _Pragma("unroll") for (int j = 0; j < 2; ++j) {                              \
    acc[i + IB][j + JB] = __builtin_amdgcn_mfma_f32_16x16x32_bf16(aF[i][0], BF[j][0], acc[i + IB][j + JB], 0, 0, 0); \
    acc[i + IB][j + JB] = __builtin_amdgcn_mfma_f32_16x16x32_bf16(aF[i][1], BF[j][1], acc[i + IB][j + JB], 0, 0, 0); \
  }                                                                            \
  __builtin_amdgcn_s_setprio(0);

  // prologue: tile 0, issue order A0,B0,B1,A1 (oldest -> newest)
  SA(0, 0, 0) SB(0, 0, 0) SB(0, 1, 0) SA(0, 1, 0)

  int cur = 0;
  for (int t = 0; t < NT - 1; ++t) {
    const u16* lA = lds + cur * 32768;
    const u16* lB = lA + 16384;
    const int nk0 = (t + 1) << 6;
    PSYNC(4)
    SA(cur ^ 1, 0, nk0) SB(cur ^ 1, 0, nk0)
    READ_A0 READ_B0
    MFMA16(0, 0, b0F)
    PSYNC(6)
    SB(cur ^ 1, 1, nk0)
    READ_B1
    MFMA16(0, 2, b1F)
    PSYNC(6)
    SA(cur ^ 1, 1, nk0)
    READ_A1
    MFMA16(4, 2, b1F)
    MFMA16(4, 0, b0F)
    cur ^= 1;
  }
  {
    const u16* lA = lds + cur * 32768;
    const u16* lB = lA + 16384;
    PSYNC(4)
    READ_A0 READ_B0
    MFMA16(0, 0, b0F)
    PSYNC(2)
    READ_B1
    MFMA16(0, 2, b1F)
    PSYNC(0)
    READ_A1
    MFMA16(4, 2, b1F)
    MFMA16(4, 0, b0F)
  }
#undef SA
#undef SB
#undef PSYNC
#undef READ_A0
#undef READ_A1
#undef READ_B0
#undef READ_B1
#undef MFMA16

  // ---- epilogue ----
  if (MODE == 1) {
#pragma unroll
    for (int j = 0; j < 4; ++j) {
      const int col = bx * 256 + wc * 64 + j * 16 + l15;   // < 1792
      const float bia = bias[ez * 1792 + col];
#pragma unroll
      for (int i = 0; i < 8; ++i)
#pragma unroll
        for (int r = 0; r < 4; ++r) {
          const int row = by * 256 + wr * 128 + i * 16 + l16 * 4 + r;
          float v = acc[i][j][r] + bia;
          v = v > 0.f ? v : 0.f;
          H[((size_t)ez * MP_ + row) * 1792 + col] = f2bf(v * gcomp[ez * MP_ + row]);
        }
    }
  } else {
#pragma unroll
    for (int j = 0; j < 4; ++j) {
      const int col = bx * 256 + wc * 64 + j * 16 + l15;
      if (col < 896) {
#pragma unroll
        for (int i = 0; i < 8; ++i)
#pragma unroll
          for (int r = 0; r < 4; ++r) {
            const int row = by * 256 + wr * 128 + i * 16 + l16 * 4 + r;
            Ye[((size_t)ez * MP_ + row) * 896 + col] = f2bf(acc[i][j][r]);
          }
      }
    }
  }
}

// ---------- combine: yT[b,s,t] = sum_e Ye[e][pos[n,e]][s] + sum_e gf[n,e]*b2[e,s] ----------
__global__ __launch_bounds__(256)
void k_combine(const u16* __restrict__ YeE, const int* __restrict__ posT,
               const float* __restrict__ gf, const float* __restrict__ b2,
               float* __restrict__ yT) {
  __shared__ float tile[32][33];
  int b = blockIdx.z;
  int t0 = blockIdx.x * 32, s0 = blockIdx.y * 32;
  int tx = threadIdx.x & 31, ty = threadIdx.x >> 5;
  int ntv = TR_ - t0; if (ntv > 32) ntv = 32;
  for (int r = ty; r < 32; r += 8) {
    float acc = 0.f;
    if (r < ntv) {
      size_t n = (size_t)b * TR_ + t0 + r;
      const int* pp = posT + n * 8;
      const float* g = gf + n * 8;
      int s = s0 + tx;
#pragma unroll
      for (int e = 0; e < 8; ++e) {
        int p = pp[e];
        if (p >= 0) {
          u32 hv = YeE[((size_t)e * MP_ + p) * 896 + s];
          acc += __builtin_bit_cast(float, hv << 16);
        }
        acc += g[e] * b2[e * 896 + s];
      }
    }
    tile[r][tx] = acc;
  }
  __syncthreads();
  for (int i = ty; i < 32; i += 8)
    if (tx < ntv)
      yT[((size_t)b * S_ + s0 + i) * TR_ + t0 + tx] = tile[tx][i];
}

// ---------- scatter + fused finalize ----------
__global__ void k_scatter(const float* __restrict__ yT, const float* __restrict__ out_in,
                          const int* __restrict__ inv, float* __restrict__ dout,
                          const float* __restrict__ allg, const float* __restrict__ zsum,
                          const float* __restrict__ zpart) {
  int i = blockIdx.x * 256 + threadIdx.x;   // < B*S*TR = 2944256 exactly
  int tr = i % TR_;
  dout[i] = out_in[i] + yT[(size_t)(i - tr) + inv[tr]];
  if (blockIdx.x == 0) {
    int tid = threadIdx.x;
    if (tid < 32) dout[2944256 + tid] = allg[tid];
    else if (tid == 32) {
      float z = *zpart;
      const int Ts[4] = {228, 291, 767, 357};
      for (int q = 0; q < 4; ++q)
        for (int j = 0; j < 2; ++j)
          z += zsum[q * 2 + j] / (float)(2 * Ts[q] * 8);
      dout[2944288] = z;
      dout[2944289] = 0.f;
    }
  }
}

extern "C" void kernel_launch(void* const* d_in, const int* in_sizes, int n_in,
                              void* d_out, int out_size, void* d_ws, size_t ws_size,
                              hipStream_t stream) {
  const float* x         = (const float*)d_in[0];
  const float* out_in    = (const float*)d_in[1];
  const float* embedding = (const float*)d_in[2];
  const int*   index     = (const int*)d_in[3];
  const float* Wsel      = (const float*)d_in[4];
  const float* bsel      = (const float*)d_in[5];
  const float* Wemb      = (const float*)d_in[6];
  const float* bemb      = (const float*)d_in[7];
  const float* Wg        = (const float*)d_in[8];
  const float* bg        = (const float*)d_in[9];
  const float* temb      = (const float*)d_in[10];
  const float* W1        = (const float*)d_in[11];
  const float* b1        = (const float*)d_in[12];
  const float* W2        = (const float*)d_in[13];
  const float* b2        = (const float*)d_in[14];
  float* dout = (float*)d_out;

  char* ws = (char*)d_ws;
  float* allg  = (float*)(ws + 0);           // 32 f
  float* zsum  = (float*)(ws + 128);         // 8 f
  float* zpart = (float*)(ws + 160);         // 1 f
  float* w2buf = (float*)(ws + 192);         // 16 f
  int*   inv   = (int*)(ws + 256);           // 1643 i -> 6828
  float* glel  = (float*)(ws + 6912);        // 24 f
  int*   cntE  = (int*)(ws + 7040);          // 8 i
  float* xmean = (float*)(ws + 8192);        // 6144 f -> 32768
  float* gf    = (float*)(ws + 32768);       // MP*8 f -> 139264
  float* o32   = (float*)(ws + 139264);      // MP*896 f -> 12066816 (reused as yT)
  float* yT    = o32;
  float* zbuf  = (float*)(ws + 139264 + (size_t)NTOK_ * S_ * 4);  // pad-region overlay
  u16*   obf   = (u16*)(ws + 12066816);      // MP*896 bf16 -> 18030592 (dense, L2-resident)
  int*   posT  = (int*)(ws + 18030592);      // NTOK*8 i -> 18135744
  int*   listE = (int*)(ws + 18135744);      // 8*MP i  -> 18242240
  float* gcomp = (float*)(ws + 18242240);    // 8*MP f  -> 18348736
  u16*   w1t   = (u16*)(ws + 18350080);      // 8*1792*896 bf16 -> 44040192
  u16*   w2tE  = (u16*)(ws + 44040192);      // 8*1024*1792 bf16 -> 73400320
  u16*   HbE   = (u16*)(ws + 73400320);      // 8*MP*1792 bf16 -> 168820736
  u16*   YeE   = (u16*)(ws + 168820736);     // 8*MP*896 bf16 -> 216530944
  // high-water 216.5 MB < 277.5 MB proven to fit (rounds 8-13 P=8 tier)

  k_init<<<7, 256, 0, stream>>>(index, inv);
  k_reduce_x<<<24, 256, 0, stream>>>(x, xmean);
  k_small_dots<<<24, 256, 0, stream>>>(xmean, Wsel, bsel, embedding, Wemb, bemb, glel);
  k_small_tail<<<1, 64, 0, stream>>>(glel, w2buf, zpart, dout + 2944290);
  k_gather<<<dim3(52, 28, 2), 256, 0, stream>>>(out_in, inv, o32, obf);
  k_gates<<<NTOK_, 256, 0, stream>>>(o32, temb, Wg, bg, w2buf, gf, zbuf);
  k_reduce_gates<<<40, 256, 0, stream>>>(gf, zbuf, allg, zsum);
  k_build_lists<<<8, 256, 0, stream>>>(gf, listE, gcomp, posT, cntE);

  // GEMM1-sparse: H_e = gcomp .* relu(obf[listE] @ W1_e^T + b1_e)  (in-staging gather)
  k_transpose<<<dim3(56, 28, 8), 256, 0, stream>>>(W1, w1t, 896, 1792, 896, (size_t)1605632);
  k_gemm8s<1><<<dim3(7, 13, 8), 512, 0, stream>>>(obf, w1t, listE, cntE, gcomp, b1, HbE, nullptr);

  // GEMM2-sparse: Ye_e = H_e @ W2_e^T (bf16), K=1792
  k_transpose<<<dim3(32, 56, 8), 256, 0, stream>>>(W2, w2tE, 1792, 896, 1792, (size_t)1835008);
  k_gemm8s<2><<<dim3(4, 13, 8), 512, 0, stream>>>(HbE, w2tE, listE, cntE, nullptr, nullptr, nullptr, YeE);

  k_combine<<<dim3(52, 28, 2), 256, 0, stream>>>(YeE, posT, gf, b2, yT);
  k_scatter<<<11501, 256, 0, stream>>>(yT, out_in, inv, dout, allg, zsum, zpart);
}

// Round 18
// 372.548 us; speedup vs baseline: 1.1220x; 1.1220x over previous
//
#include <hip/hip_runtime.h>

typedef unsigned short u16;
typedef unsigned int u32;
typedef __bf16 bf16x8 __attribute__((ext_vector_type(8)));
typedef float f32x4 __attribute__((ext_vector_type(4)));
typedef u16 u16x8 __attribute__((ext_vector_type(8)));

#define S_    896
#define TR_   1643
#define NTOK_ 3286
#define MP_   3328   // 26*128 padded token rows (per-expert row capacity)

// ---------- helpers ----------
__device__ __forceinline__ u16 f2bf(float f) {
  u32 u = __builtin_bit_cast(u32, f);
  u = (u + 0x7FFFu + ((u >> 16) & 1u)) >> 16;   // RNE
  return (u16)u;
}

__device__ __forceinline__ void gload16(const void* g, void* l) {
  __builtin_amdgcn_global_load_lds(
      (const __attribute__((address_space(1))) u32*)g,
      (__attribute__((address_space(3))) u32*)l, 16, 0, 0);
}

// ---------- init: inverse permutation + xmean zero (26 blocks: covers 6144) ----------
// xmean MUST be re-zeroed every call: k_reduce_x atomically accumulates into it
// and the harness does not re-poison between graph replays (round-5 lesson).
__global__ void k_init(const int* __restrict__ index, int* __restrict__ inv,
                       float* __restrict__ xmean) {
  int i = blockIdx.x * 256 + threadIdx.x;
  if (i < TR_) inv[index[i]] = i;
  if (i < 6144) xmean[i] = 0.f;
}

// ---------- xmean: 192-block atomic partial sums (round-18: reverted round-17's
// 24-block single-pass, which serialized 22MB on 9% of the machine, ~+30us) ----------
__global__ __launch_bounds__(256)
void k_reduce_x(const float* __restrict__ x, float* __restrict__ xmean) {
  int i = blockIdx.x * 256 + threadIdx.x;   // b*3072+d, 0..6143
  int b = i / 3072, d = i % 3072;
  int s0 = blockIdx.y * 112;
  const float* p = x + (size_t)b * S_ * 3072 + (size_t)s0 * 3072 + d;
  float s = 0.f;
  for (int t = 0; t < 112; ++t) s += p[(size_t)t * 3072];
  atomicAdd(&xmean[i], s * (1.f / (float)S_));
}

// ---------- small gating, stage 1: 24 parallel dots ----------
__global__ __launch_bounds__(256)
void k_small_dots(const float* __restrict__ xmean,
                  const float* __restrict__ Wsel, const float* __restrict__ bsel,
                  const float* __restrict__ emb,  const float* __restrict__ Wemb,
                  const float* __restrict__ bemb, float* __restrict__ glel) {
  __shared__ float red[256];
  int blk = blockIdx.x, tid = threadIdx.x;
  float s = 0.f;
  if (blk < 16) {
    int b = blk >> 3, g = blk & 7;
    for (int d = tid; d < 3072; d += 256) s += xmean[b * 3072 + d] * Wsel[d * 8 + g];
  } else {
    int g = blk - 16;
    for (int d = tid; d < 1536; d += 256) s += emb[d] * Wemb[d * 8 + g];
  }
  red[tid] = s; __syncthreads();
  for (int st = 128; st > 0; st >>= 1) { if (tid < st) red[tid] += red[tid + st]; __syncthreads(); }
  if (tid == 0) glel[blk] = red[0] + (blk < 16 ? bsel[blk & 7] : bemb[blk - 16]);
}

// ---------- small gating, stage 2: tiny tail ----------
__global__ void k_small_tail(const float* __restrict__ glel,
                             float* __restrict__ w2buf, float* __restrict__ zpart,
                             float* __restrict__ outw) {
  if (threadIdx.x != 0) return;
  const float* gl = glel;
  const float* el = glel + 16;
  float zp = 0.f;
  for (int i = 0; i < 4; ++i) {
    float e0 = el[2 * i], e1 = el[2 * i + 1];
    float m = fmaxf(e0, e1);
    float x0 = expf(e0 - m), x1 = expf(e1 - m);
    float den = x0 + x1;
    float se0 = x0 / den, se1 = x1 / den;
    zp += (e0 * e0 + e1 * e1) * 0.5f;
    float tsq = 0.f;
    for (int b = 0; b < 2; ++b) {
      float t0 = gl[b * 8 + 2 * i], t1 = gl[b * 8 + 2 * i + 1];
      tsq += t0 * t0 + t1 * t1;
      float mm = fmaxf(t0, t1);
      float y0 = expf(t0 - mm), y1 = expf(t1 - mm);
      float dd = y0 + y1;
      float w0 = (y0 / dd + se0) * 0.5f, w1 = (y1 / dd + se1) * 0.5f;
      w2buf[b * 8 + 2 * i] = w0; w2buf[b * 8 + 2 * i + 1] = w1;
      outw[b * 8 + 2 * i]  = w0; outw[b * 8 + 2 * i + 1]  = w1;
    }
    zp += tsq * 0.25f;
  }
  *zpart = zp;
}

// ---------- gather (LDS-tiled transpose; writes o32 f32 + obf bf16 dense) ----------
__global__ __launch_bounds__(256)
void k_gather(const float* __restrict__ out_in, const int* __restrict__ inv,
              float* __restrict__ o32, u16* __restrict__ obf) {
  __shared__ float tile[32][33];
  int b = blockIdx.z;
  int tr0 = blockIdx.x * 32, s0 = blockIdx.y * 32;
  int tx = threadIdx.x & 31, ty = threadIdx.x >> 5;
  int ntr = TR_ - tr0; if (ntr > 32) ntr = 32;
  for (int i = ty; i < 32; i += 8)
    tile[i][tx] = (tx < ntr) ? out_in[((size_t)b * S_ + s0 + i) * TR_ + tr0 + tx] : 0.f;
  __syncthreads();
  for (int r = ty; r < ntr; r += 8) {
    int t = inv[tr0 + r];
    size_t off = ((size_t)b * TR_ + t) * S_ + s0 + tx;
    float v = tile[tx][r];
    o32[off] = v;
    obf[off] = f2bf(v);
  }
}

// ---------- per-token gating (no atomics) ----------
__global__ __launch_bounds__(256)
void k_gates(const float* __restrict__ o32, const float* __restrict__ temb,
             const float* __restrict__ Wg, const float* __restrict__ bg,
             const float* __restrict__ w2buf, float* __restrict__ gf,
             float* __restrict__ zbuf) {
  int n = blockIdx.x;
  int b = n / TR_, t = n % TR_;
  int typ = (t < 228) ? 0 : (t < 519) ? 1 : (t < 1286) ? 2 : 3;
  int tid = threadIdx.x;
  const float* orow = o32 + (size_t)n * S_;
  const float* trow = temb + typ * S_;
  const float* W0 = Wg + (size_t)(2 * typ) * S_ * 8;

  float acc[16];
#pragma unroll
  for (int k = 0; k < 16; ++k) acc[k] = 0.f;
  for (int s = tid; s < S_; s += 256) {
    float ov = orow[s] + trow[s];
    const float4* wa = (const float4*)(W0 + s * 8);
    const float4* wb = (const float4*)(W0 + 7168 + s * 8);
    float4 a0 = wa[0], a1 = wa[1], b0 = wb[0], b1 = wb[1];
    acc[0]  += ov * a0.x; acc[1]  += ov * a0.y; acc[2]  += ov * a0.z; acc[3]  += ov * a0.w;
    acc[4]  += ov * a1.x; acc[5]  += ov * a1.y; acc[6]  += ov * a1.z; acc[7]  += ov * a1.w;
    acc[8]  += ov * b0.x; acc[9]  += ov * b0.y; acc[10] += ov * b0.z; acc[11] += ov * b0.w;
    acc[12] += ov * b1.x; acc[13] += ov * b1.y; acc[14] += ov * b1.z; acc[15] += ov * b1.w;
  }
#pragma unroll
  for (int k = 0; k < 16; ++k)
#pragma unroll
    for (int m = 1; m < 64; m <<= 1) acc[k] += __shfl_xor(acc[k], m, 64);

  __shared__ float wsum[4][16];
  __shared__ float lgsh[16];
  int w = tid >> 6, lane = tid & 63;
  if (lane == 0)
#pragma unroll
    for (int k = 0; k < 16; ++k) wsum[w][k] = acc[k];
  __syncthreads();
  if (tid < 16)
    lgsh[tid] = wsum[0][tid] + wsum[1][tid] + wsum[2][tid] + wsum[3][tid]
              + bg[(2 * typ + (tid >> 3)) * 8 + (tid & 7)];
  __syncthreads();

  if (tid == 0) {
    float g[8];
    for (int k = 0; k < 8; ++k) g[k] = 0.f;
    float zs[2];
    for (int j = 0; j < 2; ++j) {
      float l[8]; float ss = 0.f;
      for (int k = 0; k < 8; ++k) {
        float v = lgsh[j * 8 + k];
        v = v > 0.f ? v : 0.01f * v;
        l[k] = v; ss += v * v;
      }
      zs[j] = ss;
      int i0 = 0;
      for (int k = 1; k < 8; ++k) if (l[k] > l[i0]) i0 = k;
      int i1 = -1;
      for (int k = 0; k < 8; ++k) { if (k == i0) continue; if (i1 < 0 || l[k] > l[i1]) i1 = k; }
      int i2 = -1;
      for (int k = 0; k < 8; ++k) { if (k == i0 || k == i1) continue; if (i2 < 0 || l[k] > l[i2]) i2 = k; }
      float p1 = expf(l[i1] - l[i0]), p2 = expf(l[i2] - l[i0]);
      float den = 1.f + p1 + p2;
      float w2 = w2buf[b * 8 + 2 * typ + j];
      g[i0] += w2 / den; g[i1] += w2 * p1 / den; g[i2] += w2 * p2 / den;
    }
    float* gfp = gf + (size_t)n * 8;
    for (int k = 0; k < 8; ++k) gfp[k] = g[k];
    zbuf[n * 2 + 0] = zs[0];
    zbuf[n * 2 + 1] = zs[1];
  }
}

// ---------- segment reductions ----------
__global__ __launch_bounds__(256)
void k_reduce_gates(const float* __restrict__ gf, const float* __restrict__ zbuf,
                    float* __restrict__ allg, float* __restrict__ zsum) {
  __shared__ float red[256];
  const int s0a[4] = {0, 228, 519, 1286};
  const int cta[4] = {228, 291, 767, 357};
  int blk = blockIdx.x, tid = threadIdx.x;
  float s = 0.f;
  if (blk < 32) {
    int typ = blk >> 3, e = blk & 7;
    int s0 = s0a[typ], cnt = cta[typ];
    for (int i = tid; i < 2 * cnt; i += 256) {
      int bb = i / cnt, tt = s0 + i % cnt;
      s += gf[(size_t)(bb * TR_ + tt) * 8 + e];
    }
  } else {
    int idx = blk - 32, typ = idx >> 1, j = idx & 1;
    int s0 = s0a[typ], cnt = cta[typ];
    for (int i = tid; i < 2 * cnt; i += 256) {
      int bb = i / cnt, tt = s0 + i % cnt;
      s += zbuf[(size_t)(bb * TR_ + tt) * 2 + j];
    }
  }
  red[tid] = s; __syncthreads();
  for (int st = 128; st > 0; st >>= 1) { if (tid < st) red[tid] += red[tid + st]; __syncthreads(); }
  if (tid == 0) {
    if (blk < 32) allg[blk] = red[0];
    else          zsum[blk - 32] = red[0];
  }
}

// ---------- expert token-list build + tail fill ----------
__global__ __launch_bounds__(256)
void k_build_lists(const float* __restrict__ gf, int* __restrict__ listE,
                   float* __restrict__ gcomp, int* __restrict__ posT,
                   int* __restrict__ cntE) {
  __shared__ int wcnt[4];
  __shared__ int sbase;
  int e = blockIdx.x;
  int tid = threadIdx.x, lane = tid & 63, wv = tid >> 6;
  if (tid == 0) sbase = 0;
  __syncthreads();
  for (int c = 0; c < 13; ++c) {
    int n = c * 256 + tid;
    float gv = (n < NTOK_) ? gf[(size_t)n * 8 + e] : 0.f;
    bool flag = (n < NTOK_) && (gv != 0.f);
    unsigned long long m = __ballot(flag);
    if (lane == 0) wcnt[wv] = __popcll(m);
    __syncthreads();
    int prefix = 0;
    for (int w = 0; w < 4; ++w) if (w < wv) prefix += wcnt[w];
    int within = __popcll(m & ((1ull << lane) - 1ull));
    if (n < NTOK_) {
      if (flag) {
        int idx = sbase + prefix + within;
        listE[e * MP_ + idx] = n;
        gcomp[e * MP_ + idx] = gv;
        posT[(size_t)n * 8 + e] = idx;
      } else {
        posT[(size_t)n * 8 + e] = -1;
      }
    }
    __syncthreads();
    if (tid == 0) sbase += wcnt[0] + wcnt[1] + wcnt[2] + wcnt[3];
    __syncthreads();
  }
  // tail fill: active-block tail rows must read valid memory and produce H=0
  for (int idx = sbase + tid; idx < MP_; idx += 256) {
    listE[e * MP_ + idx] = 0;
    gcomp[e * MP_ + idx] = 0.f;
  }
  if (tid == 0) cntE[e] = sbase;
}

// ---------- tiled transpose f32 -> bf16 with output-row padding ----------
__global__ __launch_bounds__(256)
void k_transpose(const float* __restrict__ W, u16* __restrict__ Wt,
                 int R, int C, int ldo, size_t eo) {
  __shared__ float tile[32][33];
  int e = blockIdx.z;
  const float* Wp = W + (size_t)e * R * C;
  u16* Wtp = Wt + (size_t)e * eo;
  int c0 = blockIdx.x * 32, r0 = blockIdx.y * 32;
  int tx = threadIdx.x & 31, ty = threadIdx.x >> 5;
  for (int i = ty; i < 32; i += 8)
    tile[i][tx] = (c0 + tx < C) ? Wp[(size_t)(r0 + i) * C + c0 + tx] : 0.f;
  __syncthreads();
  for (int i = ty; i < 32; i += 8) Wtp[(size_t)(c0 + i) * ldo + r0 + tx] = f2bf(tile[tx][i]);
}

// ---------- SPARSE 256x256x64 8-wave GEMM (frozen round-9 schedule) ----------
// MODE 1: A rows gathered IN-STAGING via listE (per-lane global src of
//         global_load_lds); A = dense obf. H_e = gcomp .* relu(... + b1_e).
// MODE 2: A = compact HbE rows (direct). Ye_e = H_e @ w2tE_e^T (bf16 out).
// Blocks early-exit when by*256 >= cntE[e] (grid static for graph capture).
template <int MODE>
__global__ __launch_bounds__(512, 2)
void k_gemm8s(const u16* __restrict__ A, const u16* __restrict__ Bt,
              const int* __restrict__ listE, const int* __restrict__ cntE,
              const float* __restrict__ gcomp, const float* __restrict__ bias,
              u16* __restrict__ H, u16* __restrict__ Ye) {
  __shared__ __align__(16) u16 lds[2 * 32768];   // [buf][A:16384|B:16384] u16
  const int tid = threadIdx.x;
  const int lane = tid & 63;
  const int wid = tid >> 6;
  const int wr = wid >> 2, wc = wid & 3;

  const int K   = (MODE == 1) ? 896 : 1792;
  const int lda = K, ldb = K;
  const int nx  = (MODE == 1) ? 7 : 4;
  const int n8  = (MODE == 1) ? 91 : 52;        // blocks per expert (13 * nx)
  const size_t bes = (MODE == 1) ? 1605632u : 1835008u;  // B expert stride (u16)

  int f0 = (blockIdx.z * 13 + blockIdx.y) * nx + blockIdx.x;
  int f = (f0 & 7) * n8 + (f0 >> 3);            // bijective XCD swizzle (8*n8 total)
  const int ez = f / n8;
  const int r8 = f % n8;
  const int by = r8 / nx, bx = r8 % nx;

  const int cnt = cntE[ez];
  if (by * 256 >= cnt) return;

  const int scol = ((lane & 7) ^ (lane >> 3)) << 3;   // inverse-swizzled col chunk
  const int rl   = wid * 8 + (lane >> 3);             // row_local base

  // per-thread A source base pointers for (g,q): row_local = q*128 + g*64 + rl
  const u16* aB00; const u16* aB01; const u16* aB10; const u16* aB11;
  if (MODE == 1) {
    const int* lE = listE + ez * MP_ + by * 256;
    aB00 = A + (size_t)lE[rl]       * 896 + scol;
    aB10 = A + (size_t)lE[64 + rl]  * 896 + scol;
    aB01 = A + (size_t)lE[128 + rl] * 896 + scol;
    aB11 = A + (size_t)lE[192 + rl] * 896 + scol;
  } else {
    const u16* Ag = A + ((size_t)ez * MP_ + (size_t)by * 256) * lda;
    aB00 = Ag + (size_t)rl * lda + scol;
    aB10 = Ag + (size_t)(64 + rl) * lda + scol;
    aB01 = Ag + (size_t)(128 + rl) * lda + scol;
    aB11 = Ag + (size_t)(192 + rl) * lda + scol;
  }
  const u16* Bg = Bt + (size_t)ez * bes + (size_t)(bx * 256) * ldb;
  const int NT = K >> 6;

#define SA(buf, g, k0)                                                          \
  {                                                                             \
    gload16((g ? aB10 : aB00) + (k0),                                           \
            lds + (buf) * 32768 + ((g) * 64 + wid * 8) * 64 + lane * 8);        \
    gload16((g ? aB11 : aB01) + (k0),                                           \
            lds + (buf) * 32768 + (128 + (g) * 64 + wid * 8) * 64 + lane * 8);  \
  }
#define SB(buf, g, k0)                                                          \
  { _Pragma("unroll")                                                           \
    for (int q = 0; q < 2; ++q) {                                               \
      const int sI = q * 8 + wid;                                               \
      const int br = (sI >> 2) * 64 + (g) * 32 + (sI & 3) * 8;                  \
      const int row = br + (lane >> 3);                                         \
      gload16(Bg + (size_t)row * ldb + scol + (k0),                             \
              lds + (buf) * 32768 + 16384 + br * 64 + lane * 8);                \
    } }
#define PSYNC(N)                                             \
  asm volatile("s_waitcnt vmcnt(" #N ")" ::: "memory");      \
  __builtin_amdgcn_s_barrier();                              \
  __builtin_amdgcn_sched_barrier(0);

  const int l15 = lane & 15, l16 = lane >> 4, l7 = lane & 7;
  const int swz0 = (l16 ^ l7) << 3;
  const int swz1 = ((4 + l16) ^ l7) << 3;
  const int rA = (wr * 128 + l15) * 64;
  const int rB = (wc * 64 + l15) * 64;

  f32x4 acc[8][4] = {};
  bf16x8 aF[4][2], b0F[2][2], b1F[2][2];

#define READ_A0  _Pragma("unroll") for (int i = 0; i < 4; ++i) {               \
    aF[i][0] = *(const bf16x8*)(lA + rA + i * 1024 + swz0);                    \
    aF[i][1] = *(const bf16x8*)(lA + rA + i * 1024 + swz1); }
#define READ_A1  _Pragma("unroll") for (int i = 0; i < 4; ++i) {               \
    aF[i][0] = *(const bf16x8*)(lA + rA + (i + 4) * 1024 + swz0);              \
    aF[i][1] = *(const bf16x8*)(lA + rA + (i + 4) * 1024 + swz1); }
#define READ_B0  _Pragma("unroll") for (int j = 0; j < 2; ++j) {               \
    b0F[j][0] = *(const bf16x8*)(lB + rB + j * 1024 + swz0);                   \
    b0F[j][1] = *(const bf16x8*)(lB + rB + j * 1024 + swz1); }
#define READ_B1  _Pragma("unroll") for (int j = 0; j < 2; ++j) {               \
    b1F[j][0] = *(const bf16x8*)(lB + rB + (j + 2) * 1024 + swz0);             \
    b1F[j][1] = *(const bf16x8*)(lB + rB + (j + 2) * 1024 + swz1); }
#define MFMA16(IB, JB, BF)                                                     \
  __builtin_amdgcn_s_setprio(1);                                               \
  _Pragma("unroll") for (int i = 0; i < 4; ++i)                                \
  _Pragma("unroll") for (int j = 0; j < 2; ++j) {                              \
    acc[i + IB][j + JB] = __builtin_amdgcn_mfma_f32_16x16x32_bf16(aF[i][0], BF[j][0], acc[i + IB][j + JB], 0, 0, 0); \
    acc[i + IB][j + JB] = __builtin_amdgcn_mfma_f32_16x16x32_bf16(aF[i][1], BF[j][1], acc[i + IB][j + JB], 0, 0, 0); \
  }                                                                            \
  __builtin_amdgcn_s_setprio(0);

  // prologue: tile 0, issue order A0,B0,B1,A1 (oldest -> newest)
  SA(0, 0, 0) SB(0, 0, 0) SB(0, 1, 0) SA(0, 1, 0)

  int cur = 0;
  for (int t = 0; t < NT - 1; ++t) {
    const u16* lA = lds + cur * 32768;
    const u16* lB = lA + 16384;
    const int nk0 = (t + 1) << 6;
    PSYNC(4)
    SA(cur ^ 1, 0, nk0) SB(cur ^ 1, 0, nk0)
    READ_A0 READ_B0
    MFMA16(0, 0, b0F)
    PSYNC(6)
    SB(cur ^ 1, 1, nk0)
    READ_B1
    MFMA16(0, 2, b1F)
    PSYNC(6)
    SA(cur ^ 1, 1, nk0)
    READ_A1
    MFMA16(4, 2, b1F)
    MFMA16(4, 0, b0F)
    cur ^= 1;
  }
  {
    const u16* lA = lds + cur * 32768;
    const u16* lB = lA + 16384;
    PSYNC(4)
    READ_A0 READ_B0
    MFMA16(0, 0, b0F)
    PSYNC(2)
    READ_B1
    MFMA16(0, 2, b1F)
    PSYNC(0)
    READ_A1
    MFMA16(4, 2, b1F)
    MFMA16(4, 0, b0F)
  }
#undef SA
#undef SB
#undef PSYNC
#undef READ_A0
#undef READ_A1
#undef READ_B0
#undef READ_B1
#undef MFMA16

  // ---- epilogue ----
  if (MODE == 1) {
#pragma unroll
    for (int j = 0; j < 4; ++j) {
      const int col = bx * 256 + wc * 64 + j * 16 + l15;   // < 1792
      const float bia = bias[ez * 1792 + col];
#pragma unroll
      for (int i = 0; i < 8; ++i)
#pragma unroll
        for (int r = 0; r < 4; ++r) {
          const int row = by * 256 + wr * 128 + i * 16 + l16 * 4 + r;
          float v = acc[i][j][r] + bia;
          v = v > 0.f ? v : 0.f;
          H[((size_t)ez * MP_ + row) * 1792 + col] = f2bf(v * gcomp[ez * MP_ + row]);
        }
    }
  } else {
#pragma unroll
    for (int j = 0; j < 4; ++j) {
      const int col = bx * 256 + wc * 64 + j * 16 + l15;
      if (col < 896) {
#pragma unroll
        for (int i = 0; i < 8; ++i)
#pragma unroll
          for (int r = 0; r < 4; ++r) {
            const int row = by * 256 + wr * 128 + i * 16 + l16 * 4 + r;
            Ye[((size_t)ez * MP_ + row) * 896 + col] = f2bf(acc[i][j][r]);
          }
      }
    }
  }
}

// ---------- combine: yT[b,s,t] = sum_e Ye[e][pos[n,e]][s] + sum_e gf[n,e]*b2[e,s] ----------
__global__ __launch_bounds__(256)
void k_combine(const u16* __restrict__ YeE, const int* __restrict__ posT,
               const float* __restrict__ gf, const float* __restrict__ b2,
               float* __restrict__ yT) {
  __shared__ float tile[32][33];
  int b = blockIdx.z;
  int t0 = blockIdx.x * 32, s0 = blockIdx.y * 32;
  int tx = threadIdx.x & 31, ty = threadIdx.x >> 5;
  int ntv = TR_ - t0; if (ntv > 32) ntv = 32;
  for (int r = ty; r < 32; r += 8) {
    float acc = 0.f;
    if (r < ntv) {
      size_t n = (size_t)b * TR_ + t0 + r;
      const int* pp = posT + n * 8;
      const float* g = gf + n * 8;
      int s = s0 + tx;
#pragma unroll
      for (int e = 0; e < 8; ++e) {
        int p = pp[e];
        if (p >= 0) {
          u32 hv = YeE[((size_t)e * MP_ + p) * 896 + s];
          acc += __builtin_bit_cast(float, hv << 16);
        }
        acc += g[e] * b2[e * 896 + s];
      }
    }
    tile[r][tx] = acc;
  }
  __syncthreads();
  for (int i = ty; i < 32; i += 8)
    if (tx < ntv)
      yT[((size_t)b * S_ + s0 + i) * TR_ + t0 + tx] = tile[tx][i];
}

// ---------- scatter + fused finalize ----------
__global__ void k_scatter(const float* __restrict__ yT, const float* __restrict__ out_in,
                          const int* __restrict__ inv, float* __restrict__ dout,
                          const float* __restrict__ allg, const float* __restrict__ zsum,
                          const float* __restrict__ zpart) {
  int i = blockIdx.x * 256 + threadIdx.x;   // < B*S*TR = 2944256 exactly
  int tr = i % TR_;
  dout[i] = out_in[i] + yT[(size_t)(i - tr) + inv[tr]];
  if (blockIdx.x == 0) {
    int tid = threadIdx.x;
    if (tid < 32) dout[2944256 + tid] = allg[tid];
    else if (tid == 32) {
      float z = *zpart;
      const int Ts[4] = {228, 291, 767, 357};
      for (int q = 0; q < 4; ++q)
        for (int j = 0; j < 2; ++j)
          z += zsum[q * 2 + j] / (float)(2 * Ts[q] * 8);
      dout[2944288] = z;
      dout[2944289] = 0.f;
    }
  }
}

extern "C" void kernel_launch(void* const* d_in, const int* in_sizes, int n_in,
                              void* d_out, int out_size, void* d_ws, size_t ws_size,
                              hipStream_t stream) {
  const float* x         = (const float*)d_in[0];
  const float* out_in    = (const float*)d_in[1];
  const float* embedding = (const float*)d_in[2];
  const int*   index     = (const int*)d_in[3];
  const float* Wsel      = (const float*)d_in[4];
  const float* bsel      = (const float*)d_in[5];
  const float* Wemb      = (const float*)d_in[6];
  const float* bemb      = (const float*)d_in[7];
  const float* Wg        = (const float*)d_in[8];
  const float* bg        = (const float*)d_in[9];
  const float* temb      = (const float*)d_in[10];
  const float* W1        = (const float*)d_in[11];
  const float* b1        = (const float*)d_in[12];
  const float* W2        = (const float*)d_in[13];
  const float* b2        = (const float*)d_in[14];
  float* dout = (float*)d_out;

  char* ws = (char*)d_ws;
  float* allg  = (float*)(ws + 0);           // 32 f
  float* zsum  = (float*)(ws + 128);         // 8 f
  float* zpart = (float*)(ws + 160);         // 1 f
  float* w2buf = (float*)(ws + 192);         // 16 f
  int*   inv   = (int*)(ws + 256);           // 1643 i -> 6828
  float* glel  = (float*)(ws + 6912);        // 24 f
  int*   cntE  = (int*)(ws + 7040);          // 8 i
  float* xmean = (float*)(ws + 8192);        // 6144 f -> 32768
  float* gf    = (float*)(ws + 32768);       // MP*8 f -> 139264
  float* o32   = (float*)(ws + 139264);      // MP*896 f -> 12066816 (reused as yT)
  float* yT    = o32;
  float* zbuf  = (float*)(ws + 139264 + (size_t)NTOK_ * S_ * 4);  // pad-region overlay
  u16*   obf   = (u16*)(ws + 12066816);      // MP*896 bf16 -> 18030592 (dense, L2-resident)
  int*   posT  = (int*)(ws + 18030592);      // NTOK*8 i -> 18135744
  int*   listE = (int*)(ws + 18135744);      // 8*MP i  -> 18242240
  float* gcomp = (float*)(ws + 18242240);    // 8*MP f  -> 18348736
  u16*   w1t   = (u16*)(ws + 18350080);      // 8*1792*896 bf16 -> 44040192
  u16*   w2tE  = (u16*)(ws + 44040192);      // 8*1024*1792 bf16 -> 73400320
  u16*   HbE   = (u16*)(ws + 73400320);      // 8*MP*1792 bf16 -> 168820736
  u16*   YeE   = (u16*)(ws + 168820736);     // 8*MP*896 bf16 -> 216530944
  // high-water 216.5 MB < 277.5 MB proven to fit (rounds 8-13 P=8 tier)

  k_init<<<26, 256, 0, stream>>>(index, inv, xmean);
  k_reduce_x<<<dim3(24, 8), 256, 0, stream>>>(x, xmean);
  k_small_dots<<<24, 256, 0, stream>>>(xmean, Wsel, bsel, embedding, Wemb, bemb, glel);
  k_small_tail<<<1, 64, 0, stream>>>(glel, w2buf, zpart, dout + 2944290);
  k_gather<<<dim3(52, 28, 2), 256, 0, stream>>>(out_in, inv, o32, obf);
  k_gates<<<NTOK_, 256, 0, stream>>>(o32, temb, Wg, bg, w2buf, gf, zbuf);
  k_reduce_gates<<<40, 256, 0, stream>>>(gf, zbuf, allg, zsum);
  k_build_lists<<<8, 256, 0, stream>>>(gf, listE, gcomp, posT, cntE);

  // GEMM1-sparse: H_e = gcomp .* relu(obf[listE] @ W1_e^T + b1_e)  (in-staging gather)
  k_transpose<<<dim3(56, 28, 8), 256, 0, stream>>>(W1, w1t, 896, 1792, 896, (size_t)1605632);
  k_gemm8s<1><<<dim3(7, 13, 8), 512, 0, stream>>>(obf, w1t, listE, cntE, gcomp, b1, HbE, nullptr);

  // GEMM2-sparse: Ye_e = H_e @ W2_e^T (bf16), K=1792
  k_transpose<<<dim3(32, 56, 8), 256, 0, stream>>>(W2, w2tE, 1792, 896, 1792, (size_t)1835008);
  k_gemm8s<2><<<dim3(4, 13, 8), 512, 0, stream>>>(HbE, w2tE, listE, cntE, nullptr, nullptr, nullptr, YeE);

  k_combine<<<dim3(52, 28, 2), 256, 0, stream>>>(YeE, posT, gf, b2, yT);
  k_scatter<<<11501, 256, 0, stream>>>(yT, out_in, inv, dout, allg, zsum, zpart);
}

// Round 19
// 346.708 us; speedup vs baseline: 1.2057x; 1.0745x over previous
//
#include <hip/hip_runtime.h>

typedef unsigned short u16;
typedef unsigned int u32;
typedef __bf16 bf16x8 __attribute__((ext_vector_type(8)));
typedef float f32x4 __attribute__((ext_vector_type(4)));
typedef u16 u16x8 __attribute__((ext_vector_type(8)));

#define S_    896
#define TR_   1643
#define NTOK_ 3286
#define MP_   3328   // 26*128 padded token rows (per-expert row capacity)

// ---------- helpers ----------
__device__ __forceinline__ u16 f2bf(float f) {
  u32 u = __builtin_bit_cast(u32, f);
  u = (u + 0x7FFFu + ((u >> 16) & 1u)) >> 16;   // RNE
  return (u16)u;
}

__device__ __forceinline__ void gload16(const void* g, void* l) {
  __builtin_amdgcn_global_load_lds(
      (const __attribute__((address_space(1))) u32*)g,
      (__attribute__((address_space(3))) u32*)l, 16, 0, 0);
}

// ---------- init: inverse permutation + xmean zero (26 blocks: covers 6144) ----------
// xmean MUST be re-zeroed every call: k_reduce_x atomically accumulates into it
// and the harness does not re-poison between graph replays (round-5 lesson).
__global__ void k_init(const int* __restrict__ index, int* __restrict__ inv,
                       float* __restrict__ xmean) {
  int i = blockIdx.x * 256 + threadIdx.x;
  if (i < TR_) inv[index[i]] = i;
  if (i < 6144) xmean[i] = 0.f;
}

// ---------- xmean: 192-block atomic partial sums ----------
__global__ __launch_bounds__(256)
void k_reduce_x(const float* __restrict__ x, float* __restrict__ xmean) {
  int i = blockIdx.x * 256 + threadIdx.x;   // b*3072+d, 0..6143
  int b = i / 3072, d = i % 3072;
  int s0 = blockIdx.y * 112;
  const float* p = x + (size_t)b * S_ * 3072 + (size_t)s0 * 3072 + d;
  float s = 0.f;
  for (int t = 0; t < 112; ++t) s += p[(size_t)t * 3072];
  atomicAdd(&xmean[i], s * (1.f / (float)S_));
}

// ---------- small gating, stage 1: 24 parallel dots ----------
__global__ __launch_bounds__(256)
void k_small_dots(const float* __restrict__ xmean,
                  const float* __restrict__ Wsel, const float* __restrict__ bsel,
                  const float* __restrict__ emb,  const float* __restrict__ Wemb,
                  const float* __restrict__ bemb, float* __restrict__ glel) {
  __shared__ float red[256];
  int blk = blockIdx.x, tid = threadIdx.x;
  float s = 0.f;
  if (blk < 16) {
    int b = blk >> 3, g = blk & 7;
    for (int d = tid; d < 3072; d += 256) s += xmean[b * 3072 + d] * Wsel[d * 8 + g];
  } else {
    int g = blk - 16;
    for (int d = tid; d < 1536; d += 256) s += emb[d] * Wemb[d * 8 + g];
  }
  red[tid] = s; __syncthreads();
  for (int st = 128; st > 0; st >>= 1) { if (tid < st) red[tid] += red[tid + st]; __syncthreads(); }
  if (tid == 0) glel[blk] = red[0] + (blk < 16 ? bsel[blk & 7] : bemb[blk - 16]);
}

// ---------- small gating, stage 2: tiny tail ----------
__global__ void k_small_tail(const float* __restrict__ glel,
                             float* __restrict__ w2buf, float* __restrict__ zpart,
                             float* __restrict__ outw) {
  if (threadIdx.x != 0) return;
  const float* gl = glel;
  const float* el = glel + 16;
  float zp = 0.f;
  for (int i = 0; i < 4; ++i) {
    float e0 = el[2 * i], e1 = el[2 * i + 1];
    float m = fmaxf(e0, e1);
    float x0 = expf(e0 - m), x1 = expf(e1 - m);
    float den = x0 + x1;
    float se0 = x0 / den, se1 = x1 / den;
    zp += (e0 * e0 + e1 * e1) * 0.5f;
    float tsq = 0.f;
    for (int b = 0; b < 2; ++b) {
      float t0 = gl[b * 8 + 2 * i], t1 = gl[b * 8 + 2 * i + 1];
      tsq += t0 * t0 + t1 * t1;
      float mm = fmaxf(t0, t1);
      float y0 = expf(t0 - mm), y1 = expf(t1 - mm);
      float dd = y0 + y1;
      float w0 = (y0 / dd + se0) * 0.5f, w1 = (y1 / dd + se1) * 0.5f;
      w2buf[b * 8 + 2 * i] = w0; w2buf[b * 8 + 2 * i + 1] = w1;
      outw[b * 8 + 2 * i]  = w0; outw[b * 8 + 2 * i + 1]  = w1;
    }
    zp += tsq * 0.25f;
  }
  *zpart = zp;
}

// ---------- gather (LDS-tiled transpose; writes o32 f32 + obf bf16 dense) ----------
__global__ __launch_bounds__(256)
void k_gather(const float* __restrict__ out_in, const int* __restrict__ inv,
              float* __restrict__ o32, u16* __restrict__ obf) {
  __shared__ float tile[32][33];
  int b = blockIdx.z;
  int tr0 = blockIdx.x * 32, s0 = blockIdx.y * 32;
  int tx = threadIdx.x & 31, ty = threadIdx.x >> 5;
  int ntr = TR_ - tr0; if (ntr > 32) ntr = 32;
  for (int i = ty; i < 32; i += 8)
    tile[i][tx] = (tx < ntr) ? out_in[((size_t)b * S_ + s0 + i) * TR_ + tr0 + tx] : 0.f;
  __syncthreads();
  for (int r = ty; r < ntr; r += 8) {
    int t = inv[tr0 + r];
    size_t off = ((size_t)b * TR_ + t) * S_ + s0 + tx;
    float v = tile[tx][r];
    o32[off] = v;
    obf[off] = f2bf(v);
  }
}

// ---------- per-token gating (no atomics) ----------
__global__ __launch_bounds__(256)
void k_gates(const float* __restrict__ o32, const float* __restrict__ temb,
             const float* __restrict__ Wg, const float* __restrict__ bg,
             const float* __restrict__ w2buf, float* __restrict__ gf,
             float* __restrict__ zbuf) {
  int n = blockIdx.x;
  int b = n / TR_, t = n % TR_;
  int typ = (t < 228) ? 0 : (t < 519) ? 1 : (t < 1286) ? 2 : 3;
  int tid = threadIdx.x;
  const float* orow = o32 + (size_t)n * S_;
  const float* trow = temb + typ * S_;
  const float* W0 = Wg + (size_t)(2 * typ) * S_ * 8;

  float acc[16];
#pragma unroll
  for (int k = 0; k < 16; ++k) acc[k] = 0.f;
  for (int s = tid; s < S_; s += 256) {
    float ov = orow[s] + trow[s];
    const float4* wa = (const float4*)(W0 + s * 8);
    const float4* wb = (const float4*)(W0 + 7168 + s * 8);
    float4 a0 = wa[0], a1 = wa[1], b0 = wb[0], b1 = wb[1];
    acc[0]  += ov * a0.x; acc[1]  += ov * a0.y; acc[2]  += ov * a0.z; acc[3]  += ov * a0.w;
    acc[4]  += ov * a1.x; acc[5]  += ov * a1.y; acc[6]  += ov * a1.z; acc[7]  += ov * a1.w;
    acc[8]  += ov * b0.x; acc[9]  += ov * b0.y; acc[10] += ov * b0.z; acc[11] += ov * b0.w;
    acc[12] += ov * b1.x; acc[13] += ov * b1.y; acc[14] += ov * b1.z; acc[15] += ov * b1.w;
  }
#pragma unroll
  for (int k = 0; k < 16; ++k)
#pragma unroll
    for (int m = 1; m < 64; m <<= 1) acc[k] += __shfl_xor(acc[k], m, 64);

  __shared__ float wsum[4][16];
  __shared__ float lgsh[16];
  int w = tid >> 6, lane = tid & 63;
  if (lane == 0)
#pragma unroll
    for (int k = 0; k < 16; ++k) wsum[w][k] = acc[k];
  __syncthreads();
  if (tid < 16)
    lgsh[tid] = wsum[0][tid] + wsum[1][tid] + wsum[2][tid] + wsum[3][tid]
              + bg[(2 * typ + (tid >> 3)) * 8 + (tid & 7)];
  __syncthreads();

  if (tid == 0) {
    float g[8];
    for (int k = 0; k < 8; ++k) g[k] = 0.f;
    float zs[2];
    for (int j = 0; j < 2; ++j) {
      float l[8]; float ss = 0.f;
      for (int k = 0; k < 8; ++k) {
        float v = lgsh[j * 8 + k];
        v = v > 0.f ? v : 0.01f * v;
        l[k] = v; ss += v * v;
      }
      zs[j] = ss;
      int i0 = 0;
      for (int k = 1; k < 8; ++k) if (l[k] > l[i0]) i0 = k;
      int i1 = -1;
      for (int k = 0; k < 8; ++k) { if (k == i0) continue; if (i1 < 0 || l[k] > l[i1]) i1 = k; }
      int i2 = -1;
      for (int k = 0; k < 8; ++k) { if (k == i0 || k == i1) continue; if (i2 < 0 || l[k] > l[i2]) i2 = k; }
      float p1 = expf(l[i1] - l[i0]), p2 = expf(l[i2] - l[i0]);
      float den = 1.f + p1 + p2;
      float w2 = w2buf[b * 8 + 2 * typ + j];
      g[i0] += w2 / den; g[i1] += w2 * p1 / den; g[i2] += w2 * p2 / den;
    }
    float* gfp = gf + (size_t)n * 8;
    for (int k = 0; k < 8; ++k) gfp[k] = g[k];
    zbuf[n * 2 + 0] = zs[0];
    zbuf[n * 2 + 1] = zs[1];
  }
}

// ---------- segment reductions ----------
__global__ __launch_bounds__(256)
void k_reduce_gates(const float* __restrict__ gf, const float* __restrict__ zbuf,
                    float* __restrict__ allg, float* __restrict__ zsum) {
  __shared__ float red[256];
  const int s0a[4] = {0, 228, 519, 1286};
  const int cta[4] = {228, 291, 767, 357};
  int blk = blockIdx.x, tid = threadIdx.x;
  float s = 0.f;
  if (blk < 32) {
    int typ = blk >> 3, e = blk & 7;
    int s0 = s0a[typ], cnt = cta[typ];
    for (int i = tid; i < 2 * cnt; i += 256) {
      int bb = i / cnt, tt = s0 + i % cnt;
      s += gf[(size_t)(bb * TR_ + tt) * 8 + e];
    }
  } else {
    int idx = blk - 32, typ = idx >> 1, j = idx & 1;
    int s0 = s0a[typ], cnt = cta[typ];
    for (int i = tid; i < 2 * cnt; i += 256) {
      int bb = i / cnt, tt = s0 + i % cnt;
      s += zbuf[(size_t)(bb * TR_ + tt) * 2 + j];
    }
  }
  red[tid] = s; __syncthreads();
  for (int st = 128; st > 0; st >>= 1) { if (tid < st) red[tid] += red[tid + st]; __syncthreads(); }
  if (tid == 0) {
    if (blk < 32) allg[blk] = red[0];
    else          zsum[blk - 32] = red[0];
  }
}

// ---------- expert token-list build + tail fill ----------
__global__ __launch_bounds__(256)
void k_build_lists(const float* __restrict__ gf, int* __restrict__ listE,
                   float* __restrict__ gcomp, int* __restrict__ posT,
                   int* __restrict__ cntE) {
  __shared__ int wcnt[4];
  __shared__ int sbase;
  int e = blockIdx.x;
  int tid = threadIdx.x, lane = tid & 63, wv = tid >> 6;
  if (tid == 0) sbase = 0;
  __syncthreads();
  for (int c = 0; c < 13; ++c) {
    int n = c * 256 + tid;
    float gv = (n < NTOK_) ? gf[(size_t)n * 8 + e] : 0.f;
    bool flag = (n < NTOK_) && (gv != 0.f);
    unsigned long long m = __ballot(flag);
    if (lane == 0) wcnt[wv] = __popcll(m);
    __syncthreads();
    int prefix = 0;
    for (int w = 0; w < 4; ++w) if (w < wv) prefix += wcnt[w];
    int within = __popcll(m & ((1ull << lane) - 1ull));
    if (n < NTOK_) {
      if (flag) {
        int idx = sbase + prefix + within;
        listE[e * MP_ + idx] = n;
        gcomp[e * MP_ + idx] = gv;
        posT[(size_t)n * 8 + e] = idx;
      } else {
        posT[(size_t)n * 8 + e] = -1;
      }
    }
    __syncthreads();
    if (tid == 0) sbase += wcnt[0] + wcnt[1] + wcnt[2] + wcnt[3];
    __syncthreads();
  }
  // tail fill: active-block tail rows must read valid memory and produce H=0
  for (int idx = sbase + tid; idx < MP_; idx += 256) {
    listE[e * MP_ + idx] = 0;
    gcomp[e * MP_ + idx] = 0.f;
  }
  if (tid == 0) cntE[e] = sbase;
}

// ---------- tiled transpose f32 -> bf16 with output-row padding ----------
__global__ __launch_bounds__(256)
void k_transpose(const float* __restrict__ W, u16* __restrict__ Wt,
                 int R, int C, int ldo, size_t eo) {
  __shared__ float tile[32][33];
  int e = blockIdx.z;
  const float* Wp = W + (size_t)e * R * C;
  u16* Wtp = Wt + (size_t)e * eo;
  int c0 = blockIdx.x * 32, r0 = blockIdx.y * 32;
  int tx = threadIdx.x & 31, ty = threadIdx.x >> 5;
  for (int i = ty; i < 32; i += 8)
    tile[i][tx] = (c0 + tx < C) ? Wp[(size_t)(r0 + i) * C + c0 + tx] : 0.f;
  __syncthreads();
  for (int i = ty; i < 32; i += 8) Wtp[(size_t)(c0 + i) * ldo + r0 + tx] = f2bf(tile[tx][i]);
}

// ---------- SPARSE 256x256x64 8-wave GEMM (frozen round-9 schedule) ----------
// Round-19 change: LDS-staged COALESCED epilogue (was 128 x 2B stores/lane ->
// 2.1x write-amp, 120MB vs 58MB useful). Now: barrier, stage 16x64 bf16 wave
// sub-tile to private 2KB LDS (XOR-swizzled granules), read u16x8 slots, store
// 16B/lane full 128B lines. 16 global stores/lane instead of 128.
template <int MODE>
__global__ __launch_bounds__(512, 2)
void k_gemm8s(const u16* __restrict__ A, const u16* __restrict__ Bt,
              const int* __restrict__ listE, const int* __restrict__ cntE,
              const float* __restrict__ gcomp, const float* __restrict__ bias,
              u16* __restrict__ H, u16* __restrict__ Ye) {
  __shared__ __align__(16) u16 lds[2 * 32768];   // [buf][A:16384|B:16384] u16
  const int tid = threadIdx.x;
  const int lane = tid & 63;
  const int wid = tid >> 6;
  const int wr = wid >> 2, wc = wid & 3;

  const int K   = (MODE == 1) ? 896 : 1792;
  const int lda = K, ldb = K;
  const int nx  = (MODE == 1) ? 7 : 4;
  const int n8  = (MODE == 1) ? 91 : 52;        // blocks per expert (13 * nx)
  const size_t bes = (MODE == 1) ? 1605632u : 1835008u;  // B expert stride (u16)

  int f0 = (blockIdx.z * 13 + blockIdx.y) * nx + blockIdx.x;
  int f = (f0 & 7) * n8 + (f0 >> 3);            // bijective XCD swizzle (8*n8 total)
  const int ez = f / n8;
  const int r8 = f % n8;
  const int by = r8 / nx, bx = r8 % nx;

  const int cnt = cntE[ez];
  if (by * 256 >= cnt) return;

  const int scol = ((lane & 7) ^ (lane >> 3)) << 3;   // inverse-swizzled col chunk
  const int rl   = wid * 8 + (lane >> 3);             // row_local base

  // per-thread A source base pointers for (g,q): row_local = q*128 + g*64 + rl
  const u16* aB00; const u16* aB01; const u16* aB10; const u16* aB11;
  if (MODE == 1) {
    const int* lE = listE + ez * MP_ + by * 256;
    aB00 = A + (size_t)lE[rl]       * 896 + scol;
    aB10 = A + (size_t)lE[64 + rl]  * 896 + scol;
    aB01 = A + (size_t)lE[128 + rl] * 896 + scol;
    aB11 = A + (size_t)lE[192 + rl] * 896 + scol;
  } else {
    const u16* Ag = A + ((size_t)ez * MP_ + (size_t)by * 256) * lda;
    aB00 = Ag + (size_t)rl * lda + scol;
    aB10 = Ag + (size_t)(64 + rl) * lda + scol;
    aB01 = Ag + (size_t)(128 + rl) * lda + scol;
    aB11 = Ag + (size_t)(192 + rl) * lda + scol;
  }
  const u16* Bg = Bt + (size_t)ez * bes + (size_t)(bx * 256) * ldb;
  const int NT = K >> 6;

#define SA(buf, g, k0)                                                          \
  {                                                                             \
    gload16((g ? aB10 : aB00) + (k0),                                           \
            lds + (buf) * 32768 + ((g) * 64 + wid * 8) * 64 + lane * 8);        \
    gload16((g ? aB11 : aB01) + (k0),                                           \
            lds + (buf) * 32768 + (128 + (g) * 64 + wid * 8) * 64 + lane * 8);  \
  }
#define SB(buf, g, k0)                                                          \
  { _Pragma("unroll")                                                           \
    for (int q = 0; q < 2; ++q) {                                               \
      const int sI = q * 8 + wid;                                               \
      const int br = (sI >> 2) * 64 + (g) * 32 + (sI & 3) * 8;                  \
      const int row = br + (lane >> 3);                                         \
      gload16(Bg + (size_t)row * ldb + scol + (k0),                             \
              lds + (buf) * 32768 + 16384 + br * 64 + lane * 8);                \
    } }
#define PSYNC(N)                                             \
  asm volatile("s_waitcnt vmcnt(" #N ")" ::: "memory");      \
  __builtin_amdgcn_s_barrier();                              \
  __builtin_amdgcn_sched_barrier(0);

  const int l15 = lane & 15, l16 = lane >> 4, l7 = lane & 7;
  const int swz0 = (l16 ^ l7) << 3;
  const int swz1 = ((4 + l16) ^ l7) << 3;
  const int rA = (wr * 128 + l15) * 64;
  const int rB = (wc * 64 + l15) * 64;

  f32x4 acc[8][4] = {};
  bf16x8 aF[4][2], b0F[2][2], b1F[2][2];

#define READ_A0  _Pragma("unroll") for (int i = 0; i < 4; ++i) {               \
    aF[i][0] = *(const bf16x8*)(lA + rA + i * 1024 + swz0);                    \
    aF[i][1] = *(const bf16x8*)(lA + rA + i * 1024 + swz1); }
#define READ_A1  _Pragma("unroll") for (int i = 0; i < 4; ++i) {               \
    aF[i][0] = *(const bf16x8*)(lA + rA + (i + 4) * 1024 + swz0);              \
    aF[i][1] = *(const bf16x8*)(lA + rA + (i + 4) * 1024 + swz1); }
#define READ_B0  _Pragma("unroll") for (int j = 0; j < 2; ++j) {               \
    b0F[j][0] = *(const bf16x8*)(lB + rB + j * 1024 + swz0);                   \
    b0F[j][1] = *(const bf16x8*)(lB + rB + j * 1024 + swz1); }
#define READ_B1  _Pragma("unroll") for (int j = 0; j < 2; ++j) {               \
    b1F[j][0] = *(const bf16x8*)(lB + rB + (j + 2) * 1024 + swz0);             \
    b1F[j][1] = *(const bf16x8*)(lB + rB + (j + 2) * 1024 + swz1); }
#define MFMA16(IB, JB, BF)                                                     \
  __builtin_amdgcn_s_setprio(1);                                               \
  _Pragma("unroll") for (int i = 0; i < 4; ++i)                                \
  _Pragma("unroll") for (int j = 0; j < 2; ++j) {                              \
    acc[i + IB][j + JB] = __builtin_amdgcn_mfma_f32_16x16x32_bf16(aF[i][0], BF[j][0], acc[i + IB][j + JB], 0, 0, 0); \
    acc[i + IB][j + JB] = __builtin_amdgcn_mfma_f32_16x16x32_bf16(aF[i][1], BF[j][1], acc[i + IB][j + JB], 0, 0, 0); \
  }                                                                            \
  __builtin_amdgcn_s_setprio(0);

  // prologue: tile 0, issue order A0,B0,B1,A1 (oldest -> newest)
  SA(0, 0, 0) SB(0, 0, 0) SB(0, 1, 0) SA(0, 1, 0)

  int cur = 0;
  for (int t = 0; t < NT - 1; ++t) {
    const u16* lA = lds + cur * 32768;
    const u16* lB = lA + 16384;
    const int nk0 = (t + 1) << 6;
    PSYNC(4)
    SA(cur ^ 1, 0, nk0) SB(cur ^ 1, 0, nk0)
    READ_A0 READ_B0
    MFMA16(0, 0, b0F)
    PSYNC(6)
    SB(cur ^ 1, 1, nk0)
    READ_B1
    MFMA16(0, 2, b1F)
    PSYNC(6)
    SA(cur ^ 1, 1, nk0)
    READ_A1
    MFMA16(4, 2, b1F)
    MFMA16(4, 0, b0F)
    cur ^= 1;
  }
  {
    const u16* lA = lds + cur * 32768;
    const u16* lB = lA + 16384;
    PSYNC(4)
    READ_A0 READ_B0
    MFMA16(0, 0, b0F)
    PSYNC(2)
    READ_B1
    MFMA16(0, 2, b1F)
    PSYNC(0)
    READ_A1
    MFMA16(4, 2, b1F)
    MFMA16(4, 0, b0F)
  }
#undef SA
#undef SB
#undef PSYNC
#undef READ_A0
#undef READ_A1
#undef READ_B0
#undef READ_B1
#undef MFMA16

  // ---- epilogue: LDS-staged coalesced stores (round-19) ----
  // All waves in the block reach here (early-exit is block-uniform) -> barrier
  // is safe; after it, the K-loop LDS is dead and each wave uses a private
  // 2KB region: 16 rows x 64 cols u16, granule (16B) index XOR-swizzled by
  // (row&7) to spread write banks. Read-back is the balanced 8-lanes-per-
  // bank-group pattern (structural minimum for b128).
  __builtin_amdgcn_s_barrier();
  u16* Wst = lds + wid * 1024;
  const int fine = l15 & 7;
  const int g15 = l15 >> 3;

  if (MODE == 1) {
    float bia[4];
#pragma unroll
    for (int j = 0; j < 4; ++j)
      bia[j] = bias[ez * 1792 + bx * 256 + wc * 64 + j * 16 + l15];
#pragma unroll
    for (int i = 0; i < 8; ++i) {
#pragma unroll
      for (int r = 0; r < 4; ++r) {
        const int row_loc = l16 * 4 + r;
        const float gs = gcomp[ez * MP_ + by * 256 + wr * 128 + i * 16 + row_loc];
#pragma unroll
        for (int j = 0; j < 4; ++j) {
          float v = acc[i][j][r] + bia[j];
          v = v > 0.f ? v : 0.f;
          const int gran = j * 2 + g15;
          Wst[row_loc * 64 + ((gran ^ (row_loc & 7)) << 3) + fine] = f2bf(v * gs);
        }
      }
      asm volatile("s_waitcnt lgkmcnt(0)" ::: "memory");
      __builtin_amdgcn_sched_barrier(0);
#pragma unroll
      for (int k = 0; k < 2; ++k) {
        const int slot = k * 64 + lane;
        const int rloc = slot >> 3, g = slot & 7;
        u16x8 val = *(const u16x8*)(Wst + rloc * 64 + ((g ^ (rloc & 7)) << 3));
        const int grow = by * 256 + wr * 128 + i * 16 + rloc;
        *(u16x8*)(H + ((size_t)ez * MP_ + grow) * 1792 + bx * 256 + wc * 64 + g * 8) = val;
      }
      asm volatile("s_waitcnt lgkmcnt(0)" ::: "memory");
      __builtin_amdgcn_sched_barrier(0);
    }
  } else {
    // whole-wave col predicate: wave covers cols [bx*256+wc*64, +64) — all <896 or none
    if (bx * 256 + wc * 64 < 896) {
#pragma unroll
      for (int i = 0; i < 8; ++i) {
#pragma unroll
        for (int r = 0; r < 4; ++r) {
          const int row_loc = l16 * 4 + r;
#pragma unroll
          for (int j = 0; j < 4; ++j) {
            const int gran = j * 2 + g15;
            Wst[row_loc * 64 + ((gran ^ (row_loc & 7)) << 3) + fine] = f2bf(acc[i][j][r]);
          }
        }
        asm volatile("s_waitcnt lgkmcnt(0)" ::: "memory");
        __builtin_amdgcn_sched_barrier(0);
#pragma unroll
        for (int k = 0; k < 2; ++k) {
          const int slot = k * 64 + lane;
          const int rloc = slot >> 3, g = slot & 7;
          u16x8 val = *(const u16x8*)(Wst + rloc * 64 + ((g ^ (rloc & 7)) << 3));
          const int grow = by * 256 + wr * 128 + i * 16 + rloc;
          *(u16x8*)(Ye + ((size_t)ez * MP_ + grow) * 896 + bx * 256 + wc * 64 + g * 8) = val;
        }
        asm volatile("s_waitcnt lgkmcnt(0)" ::: "memory");
        __builtin_amdgcn_sched_barrier(0);
      }
    }
  }
}

// ---------- combine: yT[b,s,t] = sum_e Ye[e][pos[n,e]][s] + sum_e gf[n,e]*b2[e,s] ----------
__global__ __launch_bounds__(256)
void k_combine(const u16* __restrict__ YeE, const int* __restrict__ posT,
               const float* __restrict__ gf, const float* __restrict__ b2,
               float* __restrict__ yT) {
  __shared__ float tile[32][33];
  int b = blockIdx.z;
  int t0 = blockIdx.x * 32, s0 = blockIdx.y * 32;
  int tx = threadIdx.x & 31, ty = threadIdx.x >> 5;
  int ntv = TR_ - t0; if (ntv > 32) ntv = 32;
  for (int r = ty; r < 32; r += 8) {
    float acc = 0.f;
    if (r < ntv) {
      size_t n = (size_t)b * TR_ + t0 + r;
      const int* pp = posT + n * 8;
      const float* g = gf + n * 8;
      int s = s0 + tx;
#pragma unroll
      for (int e = 0; e < 8; ++e) {
        int p = pp[e];
        if (p >= 0) {
          u32 hv = YeE[((size_t)e * MP_ + p) * 896 + s];
          acc += __builtin_bit_cast(float, hv << 16);
        }
        acc += g[e] * b2[e * 896 + s];
      }
    }
    tile[r][tx] = acc;
  }
  __syncthreads();
  for (int i = ty; i < 32; i += 8)
    if (tx < ntv)
      yT[((size_t)b * S_ + s0 + i) * TR_ + t0 + tx] = tile[tx][i];
}

// ---------- scatter + fused finalize ----------
__global__ void k_scatter(const float* __restrict__ yT, const float* __restrict__ out_in,
                          const int* __restrict__ inv, float* __restrict__ dout,
                          const float* __restrict__ allg, const float* __restrict__ zsum,
                          const float* __restrict__ zpart) {
  int i = blockIdx.x * 256 + threadIdx.x;   // < B*S*TR = 2944256 exactly
  int tr = i % TR_;
  dout[i] = out_in[i] + yT[(size_t)(i - tr) + inv[tr]];
  if (blockIdx.x == 0) {
    int tid = threadIdx.x;
    if (tid < 32) dout[2944256 + tid] = allg[tid];
    else if (tid == 32) {
      float z = *zpart;
      const int Ts[4] = {228, 291, 767, 357};
      for (int q = 0; q < 4; ++q)
        for (int j = 0; j < 2; ++j)
          z += zsum[q * 2 + j] / (float)(2 * Ts[q] * 8);
      dout[2944288] = z;
      dout[2944289] = 0.f;
    }
  }
}

extern "C" void kernel_launch(void* const* d_in, const int* in_sizes, int n_in,
                              void* d_out, int out_size, void* d_ws, size_t ws_size,
                              hipStream_t stream) {
  const float* x         = (const float*)d_in[0];
  const float* out_in    = (const float*)d_in[1];
  const float* embedding = (const float*)d_in[2];
  const int*   index     = (const int*)d_in[3];
  const float* Wsel      = (const float*)d_in[4];
  const float* bsel      = (const float*)d_in[5];
  const float* Wemb      = (const float*)d_in[6];
  const float* bemb      = (const float*)d_in[7];
  const float* Wg        = (const float*)d_in[8];
  const float* bg        = (const float*)d_in[9];
  const float* temb      = (const float*)d_in[10];
  const float* W1        = (const float*)d_in[11];
  const float* b1        = (const float*)d_in[12];
  const float* W2        = (const float*)d_in[13];
  const float* b2        = (const float*)d_in[14];
  float* dout = (float*)d_out;

  char* ws = (char*)d_ws;
  float* allg  = (float*)(ws + 0);           // 32 f
  float* zsum  = (float*)(ws + 128);         // 8 f
  float* zpart = (float*)(ws + 160);         // 1 f
  float* w2buf = (float*)(ws + 192);         // 16 f
  int*   inv   = (int*)(ws + 256);           // 1643 i -> 6828
  float* glel  = (float*)(ws + 6912);        // 24 f
  int*   cntE  = (int*)(ws + 7040);          // 8 i
  float* xmean = (float*)(ws + 8192);        // 6144 f -> 32768
  float* gf    = (float*)(ws + 32768);       // MP*8 f -> 139264
  float* o32   = (float*)(ws + 139264);      // MP*896 f -> 12066816 (reused as yT)
  float* yT    = o32;
  float* zbuf  = (float*)(ws + 139264 + (size_t)NTOK_ * S_ * 4);  // pad-region overlay
  u16*   obf   = (u16*)(ws + 12066816);      // MP*896 bf16 -> 18030592 (dense, L2-resident)
  int*   posT  = (int*)(ws + 18030592);      // NTOK*8 i -> 18135744
  int*   listE = (int*)(ws + 18135744);      // 8*MP i  -> 18242240
  float* gcomp = (float*)(ws + 18242240);    // 8*MP f  -> 18348736
  u16*   w1t   = (u16*)(ws + 18350080);      // 8*1792*896 bf16 -> 44040192
  u16*   w2tE  = (u16*)(ws + 44040192);      // 8*1024*1792 bf16 -> 73400320
  u16*   HbE   = (u16*)(ws + 73400320);      // 8*MP*1792 bf16 -> 168820736
  u16*   YeE   = (u16*)(ws + 168820736);     // 8*MP*896 bf16 -> 216530944
  // high-water 216.5 MB < 277.5 MB proven to fit (rounds 8-13 P=8 tier)

  k_init<<<26, 256, 0, stream>>>(index, inv, xmean);
  k_reduce_x<<<dim3(24, 8), 256, 0, stream>>>(x, xmean);
  k_small_dots<<<24, 256, 0, stream>>>(xmean, Wsel, bsel, embedding, Wemb, bemb, glel);
  k_small_tail<<<1, 64, 0, stream>>>(glel, w2buf, zpart, dout + 2944290);
  k_gather<<<dim3(52, 28, 2), 256, 0, stream>>>(out_in, inv, o32, obf);
  k_gates<<<NTOK_, 256, 0, stream>>>(o32, temb, Wg, bg, w2buf, gf, zbuf);
  k_reduce_gates<<<40, 256, 0, stream>>>(gf, zbuf, allg, zsum);
  k_build_lists<<<8, 256, 0, stream>>>(gf, listE, gcomp, posT, cntE);

  // GEMM1-sparse: H_e = gcomp .* relu(obf[listE] @ W1_e^T + b1_e)  (in-staging gather)
  k_transpose<<<dim3(56, 28, 8), 256, 0, stream>>>(W1, w1t, 896, 1792, 896, (size_t)1605632);
  k_gemm8s<1><<<dim3(7, 13, 8), 512, 0, stream>>>(obf, w1t, listE, cntE, gcomp, b1, HbE, nullptr);

  // GEMM2-sparse: Ye_e = H_e @ W2_e^T (bf16), K=1792
  k_transpose<<<dim3(32, 56, 8), 256, 0, stream>>>(W2, w2tE, 1792, 896, 1792, (size_t)1835008);
  k_gemm8s<2><<<dim3(4, 13, 8), 512, 0, stream>>>(HbE, w2tE, listE, cntE, nullptr, nullptr, nullptr, YeE);

  k_combine<<<dim3(52, 28, 2), 256, 0, stream>>>(YeE, posT, gf, b2, yT);
  k_scatter<<<11501, 256, 0, stream>>>(yT, out_in, inv, dout, allg, zsum, zpart);
}

// Round 20
// 343.133 us; speedup vs baseline: 1.2182x; 1.0104x over previous
//
#include <hip/hip_runtime.h>

typedef unsigned short u16;
typedef unsigned int u32;
typedef __bf16 bf16x8 __attribute__((ext_vector_type(8)));
typedef float f32x4 __attribute__((ext_vector_type(4)));
typedef u16 u16x8 __attribute__((ext_vector_type(8)));

#define S_    896
#define TR_   1643
#define NTOK_ 3286
#define MP_   3328   // 26*128 padded token rows (per-expert row capacity)

// ---------- helpers ----------
__device__ __forceinline__ u16 f2bf(float f) {
  u32 u = __builtin_bit_cast(u32, f);
  u = (u + 0x7FFFu + ((u >> 16) & 1u)) >> 16;   // RNE
  return (u16)u;
}

__device__ __forceinline__ void gload16(const void* g, void* l) {
  __builtin_amdgcn_global_load_lds(
      (const __attribute__((address_space(1))) u32*)g,
      (__attribute__((address_space(3))) u32*)l, 16, 0, 0);
}

// ---------- xmean partials + inverse permutation (round-20: k_init folded in;
// non-atomic partials -> no zero-init, no replay-accumulation hazard) ----------
__global__ __launch_bounds__(256)
void k_reduce_x(const float* __restrict__ x, float* __restrict__ xpart,
                const int* __restrict__ index, int* __restrict__ inv) {
  int i = blockIdx.x * 256 + threadIdx.x;   // b*3072+d, 0..6143
  if (blockIdx.y == 0 && i < TR_) inv[index[i]] = i;
  int b = i / 3072, d = i % 3072;
  int s0 = blockIdx.y * 112;
  const float* p = x + (size_t)b * S_ * 3072 + (size_t)s0 * 3072 + d;
  float s = 0.f;
  for (int t = 0; t < 112; ++t) s += p[(size_t)t * 3072];
  xpart[blockIdx.y * 6144 + i] = s;
}

// ---------- small gating, stage 1: 24 parallel dots (sums the 8 xpart slices) ----------
__global__ __launch_bounds__(256)
void k_small_dots(const float* __restrict__ xpart,
                  const float* __restrict__ Wsel, const float* __restrict__ bsel,
                  const float* __restrict__ emb,  const float* __restrict__ Wemb,
                  const float* __restrict__ bemb, float* __restrict__ glel) {
  __shared__ float red[256];
  int blk = blockIdx.x, tid = threadIdx.x;
  float s = 0.f;
  if (blk < 16) {
    int b = blk >> 3, g = blk & 7;
    for (int d = tid; d < 3072; d += 256) {
      float xm = 0.f;
#pragma unroll
      for (int p = 0; p < 8; ++p) xm += xpart[p * 6144 + b * 3072 + d];
      s += xm * (1.f / (float)S_) * Wsel[d * 8 + g];
    }
  } else {
    int g = blk - 16;
    for (int d = tid; d < 1536; d += 256) s += emb[d] * Wemb[d * 8 + g];
  }
  red[tid] = s; __syncthreads();
  for (int st = 128; st > 0; st >>= 1) { if (tid < st) red[tid] += red[tid + st]; __syncthreads(); }
  if (tid == 0) glel[blk] = red[0] + (blk < 16 ? bsel[blk & 7] : bemb[blk - 16]);
}

// ---------- small gating, stage 2: tiny tail ----------
__global__ void k_small_tail(const float* __restrict__ glel,
                             float* __restrict__ w2buf, float* __restrict__ zpart,
                             float* __restrict__ outw) {
  if (threadIdx.x != 0) return;
  const float* gl = glel;
  const float* el = glel + 16;
  float zp = 0.f;
  for (int i = 0; i < 4; ++i) {
    float e0 = el[2 * i], e1 = el[2 * i + 1];
    float m = fmaxf(e0, e1);
    float x0 = expf(e0 - m), x1 = expf(e1 - m);
    float den = x0 + x1;
    float se0 = x0 / den, se1 = x1 / den;
    zp += (e0 * e0 + e1 * e1) * 0.5f;
    float tsq = 0.f;
    for (int b = 0; b < 2; ++b) {
      float t0 = gl[b * 8 + 2 * i], t1 = gl[b * 8 + 2 * i + 1];
      tsq += t0 * t0 + t1 * t1;
      float mm = fmaxf(t0, t1);
      float y0 = expf(t0 - mm), y1 = expf(t1 - mm);
      float dd = y0 + y1;
      float w0 = (y0 / dd + se0) * 0.5f, w1 = (y1 / dd + se1) * 0.5f;
      w2buf[b * 8 + 2 * i] = w0; w2buf[b * 8 + 2 * i + 1] = w1;
      outw[b * 8 + 2 * i]  = w0; outw[b * 8 + 2 * i + 1]  = w1;
    }
    zp += tsq * 0.25f;
  }
  *zpart = zp;
}

// ---------- gather (LDS-tiled transpose; writes o32 f32 + obf bf16 dense) ----------
__global__ __launch_bounds__(256)
void k_gather(const float* __restrict__ out_in, const int* __restrict__ inv,
              float* __restrict__ o32, u16* __restrict__ obf) {
  __shared__ float tile[32][33];
  int b = blockIdx.z;
  int tr0 = blockIdx.x * 32, s0 = blockIdx.y * 32;
  int tx = threadIdx.x & 31, ty = threadIdx.x >> 5;
  int ntr = TR_ - tr0; if (ntr > 32) ntr = 32;
  for (int i = ty; i < 32; i += 8)
    tile[i][tx] = (tx < ntr) ? out_in[((size_t)b * S_ + s0 + i) * TR_ + tr0 + tx] : 0.f;
  __syncthreads();
  for (int r = ty; r < ntr; r += 8) {
    int t = inv[tr0 + r];
    size_t off = ((size_t)b * TR_ + t) * S_ + s0 + tx;
    float v = tile[tx][r];
    o32[off] = v;
    obf[off] = f2bf(v);
  }
}

// ---------- per-token gating (no atomics) ----------
__global__ __launch_bounds__(256)
void k_gates(const float* __restrict__ o32, const float* __restrict__ temb,
             const float* __restrict__ Wg, const float* __restrict__ bg,
             const float* __restrict__ w2buf, float* __restrict__ gf,
             float* __restrict__ zbuf) {
  int n = blockIdx.x;
  int b = n / TR_, t = n % TR_;
  int typ = (t < 228) ? 0 : (t < 519) ? 1 : (t < 1286) ? 2 : 3;
  int tid = threadIdx.x;
  const float* orow = o32 + (size_t)n * S_;
  const float* trow = temb + typ * S_;
  const float* W0 = Wg + (size_t)(2 * typ) * S_ * 8;

  float acc[16];
#pragma unroll
  for (int k = 0; k < 16; ++k) acc[k] = 0.f;
  for (int s = tid; s < S_; s += 256) {
    float ov = orow[s] + trow[s];
    const float4* wa = (const float4*)(W0 + s * 8);
    const float4* wb = (const float4*)(W0 + 7168 + s * 8);
    float4 a0 = wa[0], a1 = wa[1], b0 = wb[0], b1 = wb[1];
    acc[0]  += ov * a0.x; acc[1]  += ov * a0.y; acc[2]  += ov * a0.z; acc[3]  += ov * a0.w;
    acc[4]  += ov * a1.x; acc[5]  += ov * a1.y; acc[6]  += ov * a1.z; acc[7]  += ov * a1.w;
    acc[8]  += ov * b0.x; acc[9]  += ov * b0.y; acc[10] += ov * b0.z; acc[11] += ov * b0.w;
    acc[12] += ov * b1.x; acc[13] += ov * b1.y; acc[14] += ov * b1.z; acc[15] += ov * b1.w;
  }
#pragma unroll
  for (int k = 0; k < 16; ++k)
#pragma unroll
    for (int m = 1; m < 64; m <<= 1) acc[k] += __shfl_xor(acc[k], m, 64);

  __shared__ float wsum[4][16];
  __shared__ float lgsh[16];
  int w = tid >> 6, lane = tid & 63;
  if (lane == 0)
#pragma unroll
    for (int k = 0; k < 16; ++k) wsum[w][k] = acc[k];
  __syncthreads();
  if (tid < 16)
    lgsh[tid] = wsum[0][tid] + wsum[1][tid] + wsum[2][tid] + wsum[3][tid]
              + bg[(2 * typ + (tid >> 3)) * 8 + (tid & 7)];
  __syncthreads();

  if (tid == 0) {
    float g[8];
    for (int k = 0; k < 8; ++k) g[k] = 0.f;
    float zs[2];
    for (int j = 0; j < 2; ++j) {
      float l[8]; float ss = 0.f;
      for (int k = 0; k < 8; ++k) {
        float v = lgsh[j * 8 + k];
        v = v > 0.f ? v : 0.01f * v;
        l[k] = v; ss += v * v;
      }
      zs[j] = ss;
      int i0 = 0;
      for (int k = 1; k < 8; ++k) if (l[k] > l[i0]) i0 = k;
      int i1 = -1;
      for (int k = 0; k < 8; ++k) { if (k == i0) continue; if (i1 < 0 || l[k] > l[i1]) i1 = k; }
      int i2 = -1;
      for (int k = 0; k < 8; ++k) { if (k == i0 || k == i1) continue; if (i2 < 0 || l[k] > l[i2]) i2 = k; }
      float p1 = expf(l[i1] - l[i0]), p2 = expf(l[i2] - l[i0]);
      float den = 1.f + p1 + p2;
      float w2 = w2buf[b * 8 + 2 * typ + j];
      g[i0] += w2 / den; g[i1] += w2 * p1 / den; g[i2] += w2 * p2 / den;
    }
    float* gfp = gf + (size_t)n * 8;
    for (int k = 0; k < 8; ++k) gfp[k] = g[k];
    zbuf[n * 2 + 0] = zs[0];
    zbuf[n * 2 + 1] = zs[1];
  }
}

// ---------- merged segment reductions + expert list build (round-20) ----------
// blk<32: allg; blk 32..39: zsum; blk 40..47: build listE/gcomp/posT/cntE (e=blk-40)
__global__ __launch_bounds__(256)
void k_reduce_build(const float* __restrict__ gf, const float* __restrict__ zbuf,
                    float* __restrict__ allg, float* __restrict__ zsum,
                    int* __restrict__ listE, float* __restrict__ gcomp,
                    int* __restrict__ posT, int* __restrict__ cntE) {
  int blk = blockIdx.x, tid = threadIdx.x;
  if (blk < 40) {
    __shared__ float red[256];
    const int s0a[4] = {0, 228, 519, 1286};
    const int cta[4] = {228, 291, 767, 357};
    float s = 0.f;
    if (blk < 32) {
      int typ = blk >> 3, e = blk & 7;
      int s0 = s0a[typ], cnt = cta[typ];
      for (int i = tid; i < 2 * cnt; i += 256) {
        int bb = i / cnt, tt = s0 + i % cnt;
        s += gf[(size_t)(bb * TR_ + tt) * 8 + e];
      }
    } else {
      int idx = blk - 32, typ = idx >> 1, j = idx & 1;
      int s0 = s0a[typ], cnt = cta[typ];
      for (int i = tid; i < 2 * cnt; i += 256) {
        int bb = i / cnt, tt = s0 + i % cnt;
        s += zbuf[(size_t)(bb * TR_ + tt) * 2 + j];
      }
    }
    red[tid] = s; __syncthreads();
    for (int st = 128; st > 0; st >>= 1) { if (tid < st) red[tid] += red[tid + st]; __syncthreads(); }
    if (tid == 0) {
      if (blk < 32) allg[blk] = red[0];
      else          zsum[blk - 32] = red[0];
    }
  } else {
    __shared__ int wcnt[4];
    __shared__ int sbase;
    int e = blk - 40;
    int lane = tid & 63, wv = tid >> 6;
    if (tid == 0) sbase = 0;
    __syncthreads();
    for (int c = 0; c < 13; ++c) {
      int n = c * 256 + tid;
      float gv = (n < NTOK_) ? gf[(size_t)n * 8 + e] : 0.f;
      bool flag = (n < NTOK_) && (gv != 0.f);
      unsigned long long m = __ballot(flag);
      if (lane == 0) wcnt[wv] = __popcll(m);
      __syncthreads();
      int prefix = 0;
      for (int w = 0; w < 4; ++w) if (w < wv) prefix += wcnt[w];
      int within = __popcll(m & ((1ull << lane) - 1ull));
      if (n < NTOK_) {
        if (flag) {
          int idx = sbase + prefix + within;
          listE[e * MP_ + idx] = n;
          gcomp[e * MP_ + idx] = gv;
          posT[(size_t)n * 8 + e] = idx;
        } else {
          posT[(size_t)n * 8 + e] = -1;
        }
      }
      __syncthreads();
      if (tid == 0) sbase += wcnt[0] + wcnt[1] + wcnt[2] + wcnt[3];
      __syncthreads();
    }
    for (int idx = sbase + tid; idx < MP_; idx += 256) {
      listE[e * MP_ + idx] = 0;
      gcomp[e * MP_ + idx] = 0.f;
    }
    if (tid == 0) cntE[e] = sbase;
  }
}

// ---------- merged weight transposes, one dispatch (round-20) ----------
// flat blocks: [0,12544) -> W1 (e,y<28,x<56); [12544,26880) -> W2 (e,y<56,x<32)
__global__ __launch_bounds__(256)
void k_transposeAll(const float* __restrict__ W1, u16* __restrict__ w1t,
                    const float* __restrict__ W2, u16* __restrict__ w2tE) {
  __shared__ float tile[32][33];
  int idx = blockIdx.x;
  const float* W; u16* Wt; int R, C, ldo; size_t eo; int e, bx_, by_;
  if (idx < 12544) {
    e = idx / 1568; int rem = idx % 1568; bx_ = rem % 56; by_ = rem / 56;
    W = W1; Wt = w1t; R = 896; C = 1792; ldo = 896; eo = 1605632u;
  } else {
    int i2 = idx - 12544;
    e = i2 / 1792; int rem = i2 % 1792; bx_ = rem % 32; by_ = rem / 32;
    W = W2; Wt = w2tE; R = 1792; C = 896; ldo = 1792; eo = 1835008u;
  }
  const float* Wp = W + (size_t)e * R * C;
  u16* Wtp = Wt + (size_t)e * eo;
  int c0 = bx_ * 32, r0 = by_ * 32;
  int tx = threadIdx.x & 31, ty = threadIdx.x >> 5;
  for (int i = ty; i < 32; i += 8)
    tile[i][tx] = (c0 + tx < C) ? Wp[(size_t)(r0 + i) * C + c0 + tx] : 0.f;
  __syncthreads();
  for (int i = ty; i < 32; i += 8) Wtp[(size_t)(c0 + i) * ldo + r0 + tx] = f2bf(tile[tx][i]);
}

// ---------- SPARSE 256x256x64 8-wave GEMM (frozen round-9 schedule,
// round-19 LDS-staged coalesced epilogue) ----------
template <int MODE>
__global__ __launch_bounds__(512, 2)
void k_gemm8s(const u16* __restrict__ A, const u16* __restrict__ Bt,
              const int* __restrict__ listE, const int* __restrict__ cntE,
              const float* __restrict__ gcomp, const float* __restrict__ bias,
              u16* __restrict__ H, u16* __restrict__ Ye) {
  __shared__ __align__(16) u16 lds[2 * 32768];   // [buf][A:16384|B:16384] u16
  const int tid = threadIdx.x;
  const int lane = tid & 63;
  const int wid = tid >> 6;
  const int wr = wid >> 2, wc = wid & 3;

  const int K   = (MODE == 1) ? 896 : 1792;
  const int lda = K, ldb = K;
  const int nx  = (MODE == 1) ? 7 : 4;
  const int n8  = (MODE == 1) ? 91 : 52;        // blocks per expert (13 * nx)
  const size_t bes = (MODE == 1) ? 1605632u : 1835008u;  // B expert stride (u16)

  int f0 = (blockIdx.z * 13 + blockIdx.y) * nx + blockIdx.x;
  int f = (f0 & 7) * n8 + (f0 >> 3);            // bijective XCD swizzle (8*n8 total)
  const int ez = f / n8;
  const int r8 = f % n8;
  const int by = r8 / nx, bx = r8 % nx;

  const int cnt = cntE[ez];
  if (by * 256 >= cnt) return;

  const int scol = ((lane & 7) ^ (lane >> 3)) << 3;   // inverse-swizzled col chunk
  const int rl   = wid * 8 + (lane >> 3);             // row_local base

  const u16* aB00; const u16* aB01; const u16* aB10; const u16* aB11;
  if (MODE == 1) {
    const int* lE = listE + ez * MP_ + by * 256;
    aB00 = A + (size_t)lE[rl]       * 896 + scol;
    aB10 = A + (size_t)lE[64 + rl]  * 896 + scol;
    aB01 = A + (size_t)lE[128 + rl] * 896 + scol;
    aB11 = A + (size_t)lE[192 + rl] * 896 + scol;
  } else {
    const u16* Ag = A + ((size_t)ez * MP_ + (size_t)by * 256) * lda;
    aB00 = Ag + (size_t)rl * lda + scol;
    aB10 = Ag + (size_t)(64 + rl) * lda + scol;
    aB01 = Ag + (size_t)(128 + rl) * lda + scol;
    aB11 = Ag + (size_t)(192 + rl) * lda + scol;
  }
  const u16* Bg = Bt + (size_t)ez * bes + (size_t)(bx * 256) * ldb;
  const int NT = K >> 6;

#define SA(buf, g, k0)                                                          \
  {                                                                             \
    gload16((g ? aB10 : aB00) + (k0),                                           \
            lds + (buf) * 32768 + ((g) * 64 + wid * 8) * 64 + lane * 8);        \
    gload16((g ? aB11 : aB01) + (k0),                                           \
            lds + (buf) * 32768 + (128 + (g) * 64 + wid * 8) * 64 + lane * 8);  \
  }
#define SB(buf, g, k0)                                                          \
  { _Pragma("unroll")                                                           \
    for (int q = 0; q < 2; ++q) {                                               \
      const int sI = q * 8 + wid;                                               \
      const int br = (sI >> 2) * 64 + (g) * 32 + (sI & 3) * 8;                  \
      const int row = br + (lane >> 3);                                         \
      gload16(Bg + (size_t)row * ldb + scol + (k0),                             \
              lds + (buf) * 32768 + 16384 + br * 64 + lane * 8);                \
    } }
#define PSYNC(N)                                             \
  asm volatile("s_waitcnt vmcnt(" #N ")" ::: "memory");      \
  __builtin_amdgcn_s_barrier();                              \
  __builtin_amdgcn_sched_barrier(0);

  const int l15 = lane & 15, l16 = lane >> 4, l7 = lane & 7;
  const int swz0 = (l16 ^ l7) << 3;
  const int swz1 = ((4 + l16) ^ l7) << 3;
  const int rA = (wr * 128 + l15) * 64;
  const int rB = (wc * 64 + l15) * 64;

  f32x4 acc[8][4] = {};
  bf16x8 aF[4][2], b0F[2][2], b1F[2][2];

#define READ_A0  _Pragma("unroll") for (int i = 0; i < 4; ++i) {               \
    aF[i][0] = *(const bf16x8*)(lA + rA + i * 1024 + swz0);                    \
    aF[i][1] = *(const bf16x8*)(lA + rA + i * 1024 + swz1); }
#define READ_A1  _Pragma("unroll") for (int i = 0; i < 4; ++i) {               \
    aF[i][0] = *(const bf16x8*)(lA + rA + (i + 4) * 1024 + swz0);              \
    aF[i][1] = *(const bf16x8*)(lA + rA + (i + 4) * 1024 + swz1); }
#define READ_B0  _Pragma("unroll") for (int j = 0; j < 2; ++j) {               \
    b0F[j][0] = *(const bf16x8*)(lB + rB + j * 1024 + swz0);                   \
    b0F[j][1] = *(const bf16x8*)(lB + rB + j * 1024 + swz1); }
#define READ_B1  _Pragma("unroll") for (int j = 0; j < 2; ++j) {               \
    b1F[j][0] = *(const bf16x8*)(lB + rB + (j + 2) * 1024 + swz0);             \
    b1F[j][1] = *(const bf16x8*)(lB + rB + (j + 2) * 1024 + swz1); }
#define MFMA16(IB, JB, BF)                                                     \
  __builtin_amdgcn_s_setprio(1);                                               \
  _Pragma("unroll") for (int i = 0; i < 4; ++i)                                \
  _Pragma("unroll") for (int j = 0; j < 2; ++j) {                              \
    acc[i + IB][j + JB] = __builtin_amdgcn_mfma_f32_16x16x32_bf16(aF[i][0], BF[j][0], acc[i + IB][j + JB], 0, 0, 0); \
    acc[i + IB][j + JB] = __builtin_amdgcn_mfma_f32_16x16x32_bf16(aF[i][1], BF[j][1], acc[i + IB][j + JB], 0, 0, 0); \
  }                                                                            \
  __builtin_amdgcn_s_setprio(0);

  // prologue: tile 0, issue order A0,B0,B1,A1 (oldest -> newest)
  SA(0, 0, 0) SB(0, 0, 0) SB(0, 1, 0) SA(0, 1, 0)

  int cur = 0;
  for (int t = 0; t < NT - 1; ++t) {
    const u16* lA = lds + cur * 32768;
    const u16* lB = lA + 16384;
    const int nk0 = (t + 1) << 6;
    PSYNC(4)
    SA(cur ^ 1, 0, nk0) SB(cur ^ 1, 0, nk0)
    READ_A0 READ_B0
    MFMA16(0, 0, b0F)
    PSYNC(6)
    SB(cur ^ 1, 1, nk0)
    READ_B1
    MFMA16(0, 2, b1F)
    PSYNC(6)
    SA(cur ^ 1, 1, nk0)
    READ_A1
    MFMA16(4, 2, b1F)
    MFMA16(4, 0, b0F)
    cur ^= 1;
  }
  {
    const u16* lA = lds + cur * 32768;
    const u16* lB = lA + 16384;
    PSYNC(4)
    READ_A0 READ_B0
    MFMA16(0, 0, b0F)
    PSYNC(2)
    READ_B1
    MFMA16(0, 2, b1F)
    PSYNC(0)
    READ_A1
    MFMA16(4, 2, b1F)
    MFMA16(4, 0, b0F)
  }
#undef SA
#undef SB
#undef PSYNC
#undef READ_A0
#undef READ_A1
#undef READ_B0
#undef READ_B1
#undef MFMA16

  // ---- epilogue: LDS-staged coalesced stores (round-19) ----
  __builtin_amdgcn_s_barrier();
  u16* Wst = lds + wid * 1024;
  const int fine = l15 & 7;
  const int g15 = l15 >> 3;

  if (MODE == 1) {
    float bia[4];
#pragma unroll
    for (int j = 0; j < 4; ++j)
      bia[j] = bias[ez * 1792 + bx * 256 + wc * 64 + j * 16 + l15];
#pragma unroll
    for (int i = 0; i < 8; ++i) {
#pragma unroll
      for (int r = 0; r < 4; ++r) {
        const int row_loc = l16 * 4 + r;
        const float gs = gcomp[ez * MP_ + by * 256 + wr * 128 + i * 16 + row_loc];
#pragma unroll
        for (int j = 0; j < 4; ++j) {
          float v = acc[i][j][r] + bia[j];
          v = v > 0.f ? v : 0.f;
          const int gran = j * 2 + g15;
          Wst[row_loc * 64 + ((gran ^ (row_loc & 7)) << 3) + fine] = f2bf(v * gs);
        }
      }
      asm volatile("s_waitcnt lgkmcnt(0)" ::: "memory");
      __builtin_amdgcn_sched_barrier(0);
#pragma unroll
      for (int k = 0; k < 2; ++k) {
        const int slot = k * 64 + lane;
        const int rloc = slot >> 3, g = slot & 7;
        u16x8 val = *(const u16x8*)(Wst + rloc * 64 + ((g ^ (rloc & 7)) << 3));
        const int grow = by * 256 + wr * 128 + i * 16 + rloc;
        *(u16x8*)(H + ((size_t)ez * MP_ + grow) * 1792 + bx * 256 + wc * 64 + g * 8) = val;
      }
      asm volatile("s_waitcnt lgkmcnt(0)" ::: "memory");
      __builtin_amdgcn_sched_barrier(0);
    }
  } else {
    if (bx * 256 + wc * 64 < 896) {
#pragma unroll
      for (int i = 0; i < 8; ++i) {
#pragma unroll
        for (int r = 0; r < 4; ++r) {
          const int row_loc = l16 * 4 + r;
#pragma unroll
          for (int j = 0; j < 4; ++j) {
            const int gran = j * 2 + g15;
            Wst[row_loc * 64 + ((gran ^ (row_loc & 7)) << 3) + fine] = f2bf(acc[i][j][r]);
          }
        }
        asm volatile("s_waitcnt lgkmcnt(0)" ::: "memory");
        __builtin_amdgcn_sched_barrier(0);
#pragma unroll
        for (int k = 0; k < 2; ++k) {
          const int slot = k * 64 + lane;
          const int rloc = slot >> 3, g = slot & 7;
          u16x8 val = *(const u16x8*)(Wst + rloc * 64 + ((g ^ (rloc & 7)) << 3));
          const int grow = by * 256 + wr * 128 + i * 16 + rloc;
          *(u16x8*)(Ye + ((size_t)ez * MP_ + grow) * 896 + bx * 256 + wc * 64 + g * 8) = val;
        }
        asm volatile("s_waitcnt lgkmcnt(0)" ::: "memory");
        __builtin_amdgcn_sched_barrier(0);
      }
    }
  }
}

// ---------- combine: yT[b,s,t] = sum_e Ye[e][pos[n,e]][s] + sum_e gf[n,e]*b2[e,s] ----------
__global__ __launch_bounds__(256)
void k_combine(const u16* __restrict__ YeE, const int* __restrict__ posT,
               const float* __restrict__ gf, const float* __restrict__ b2,
               float* __restrict__ yT) {
  __shared__ float tile[32][33];
  int b = blockIdx.z;
  int t0 = blockIdx.x * 32, s0 = blockIdx.y * 32;
  int tx = threadIdx.x & 31, ty = threadIdx.x >> 5;
  int ntv = TR_ - t0; if (ntv > 32) ntv = 32;
  for (int r = ty; r < 32; r += 8) {
    float acc = 0.f;
    if (r < ntv) {
      size_t n = (size_t)b * TR_ + t0 + r;
      const int* pp = posT + n * 8;
      const float* g = gf + n * 8;
      int s = s0 + tx;
#pragma unroll
      for (int e = 0; e < 8; ++e) {
        int p = pp[e];
        if (p >= 0) {
          u32 hv = YeE[((size_t)e * MP_ + p) * 896 + s];
          acc += __builtin_bit_cast(float, hv << 16);
        }
        acc += g[e] * b2[e * 896 + s];
      }
    }
    tile[r][tx] = acc;
  }
  __syncthreads();
  for (int i = ty; i < 32; i += 8)
    if (tx < ntv)
      yT[((size_t)b * S_ + s0 + i) * TR_ + t0 + tx] = tile[tx][i];
}

// ---------- scatter + fused finalize ----------
__global__ void k_scatter(const float* __restrict__ yT, const float* __restrict__ out_in,
                          const int* __restrict__ inv, float* __restrict__ dout,
                          const float* __restrict__ allg, const float* __restrict__ zsum,
                          const float* __restrict__ zpart) {
  int i = blockIdx.x * 256 + threadIdx.x;   // < B*S*TR = 2944256 exactly
  int tr = i % TR_;
  dout[i] = out_in[i] + yT[(size_t)(i - tr) + inv[tr]];
  if (blockIdx.x == 0) {
    int tid = threadIdx.x;
    if (tid < 32) dout[2944256 + tid] = allg[tid];
    else if (tid == 32) {
      float z = *zpart;
      const int Ts[4] = {228, 291, 767, 357};
      for (int q = 0; q < 4; ++q)
        for (int j = 0; j < 2; ++j)
          z += zsum[q * 2 + j] / (float)(2 * Ts[q] * 8);
      dout[2944288] = z;
      dout[2944289] = 0.f;
    }
  }
}

extern "C" void kernel_launch(void* const* d_in, const int* in_sizes, int n_in,
                              void* d_out, int out_size, void* d_ws, size_t ws_size,
                              hipStream_t stream) {
  const float* x         = (const float*)d_in[0];
  const float* out_in    = (const float*)d_in[1];
  const float* embedding = (const float*)d_in[2];
  const int*   index     = (const int*)d_in[3];
  const float* Wsel      = (const float*)d_in[4];
  const float* bsel      = (const float*)d_in[5];
  const float* Wemb      = (const float*)d_in[6];
  const float* bemb      = (const float*)d_in[7];
  const float* Wg        = (const float*)d_in[8];
  const float* bg        = (const float*)d_in[9];
  const float* temb      = (const float*)d_in[10];
  const float* W1        = (const float*)d_in[11];
  const float* b1        = (const float*)d_in[12];
  const float* W2        = (const float*)d_in[13];
  const float* b2        = (const float*)d_in[14];
  float* dout = (float*)d_out;

  char* ws = (char*)d_ws;
  float* allg  = (float*)(ws + 0);           // 32 f
  float* zsum  = (float*)(ws + 128);         // 8 f
  float* zpart = (float*)(ws + 160);         // 1 f
  float* w2buf = (float*)(ws + 192);         // 16 f
  int*   inv   = (int*)(ws + 256);           // 1643 i -> 6828
  float* glel  = (float*)(ws + 6912);        // 24 f
  int*   cntE  = (int*)(ws + 7040);          // 8 i
  float* gf    = (float*)(ws + 32768);       // MP*8 f -> 139264
  float* o32   = (float*)(ws + 139264);      // MP*896 f -> 12066816 (reused as yT)
  float* yT    = o32;
  float* zbuf  = (float*)(ws + 139264 + (size_t)NTOK_ * S_ * 4);  // pad-region overlay
  u16*   obf   = (u16*)(ws + 12066816);      // MP*896 bf16 -> 18030592 (dense, L2-resident)
  int*   posT  = (int*)(ws + 18030592);      // NTOK*8 i -> 18135744
  int*   listE = (int*)(ws + 18135744);      // 8*MP i  -> 18242240
  float* gcomp = (float*)(ws + 18242240);    // 8*MP f  -> 18348736
  u16*   w1t   = (u16*)(ws + 18350080);      // 8*1792*896 bf16 -> 44040192
  u16*   w2tE  = (u16*)(ws + 44040192);      // 8*1024*1792 bf16 -> 73400320
  u16*   HbE   = (u16*)(ws + 73400320);      // 8*MP*1792 bf16 -> 168820736
  u16*   YeE   = (u16*)(ws + 168820736);     // 8*MP*896 bf16 -> 216530944
  float* xpart = (float*)(ws + 216530944);   // 8*6144 f -> 216727552
  // high-water 216.7 MB < 277.5 MB proven to fit (rounds 8-13 P=8 tier)

  k_reduce_x<<<dim3(24, 8), 256, 0, stream>>>(x, xpart, index, inv);
  k_small_dots<<<24, 256, 0, stream>>>(xpart, Wsel, bsel, embedding, Wemb, bemb, glel);
  k_small_tail<<<1, 64, 0, stream>>>(glel, w2buf, zpart, dout + 2944290);
  k_gather<<<dim3(52, 28, 2), 256, 0, stream>>>(out_in, inv, o32, obf);
  k_gates<<<NTOK_, 256, 0, stream>>>(o32, temb, Wg, bg, w2buf, gf, zbuf);
  k_reduce_build<<<48, 256, 0, stream>>>(gf, zbuf, allg, zsum, listE, gcomp, posT, cntE);
  k_transposeAll<<<26880, 256, 0, stream>>>(W1, w1t, W2, w2tE);

  // GEMM1-sparse: H_e = gcomp .* relu(obf[listE] @ W1_e^T + b1_e)  (in-staging gather)
  k_gemm8s<1><<<dim3(7, 13, 8), 512, 0, stream>>>(obf, w1t, listE, cntE, gcomp, b1, HbE, nullptr);

  // GEMM2-sparse: Ye_e = H_e @ W2_e^T (bf16), K=1792
  k_gemm8s<2><<<dim3(4, 13, 8), 512, 0, stream>>>(HbE, w2tE, listE, cntE, nullptr, nullptr, nullptr, YeE);

  k_combine<<<dim3(52, 28, 2), 256, 0, stream>>>(YeE, posT, gf, b2, yT);
  k_scatter<<<11501, 256, 0, stream>>>(yT, out_in, inv, dout, allg, zsum, zpart);
}